// Round 14
// baseline (938.574 us; speedup 1.0000x reference)
//
#include <hip/hip_runtime.h>
#include <hip/hip_bf16.h>

typedef __hip_bfloat16 bf16;
typedef __attribute__((ext_vector_type(8))) short short8;
typedef __attribute__((ext_vector_type(4))) float f32x4;

__device__ __forceinline__ float b2f(bf16 v){ return __bfloat162float(v); }
__device__ __forceinline__ unsigned short f2bits(float v){
  bf16 h = __float2bfloat16(v);
  return *reinterpret_cast<unsigned short*>(&h);
}

__device__ __forceinline__ void gload16(const bf16* g, bf16* l){
  __builtin_amdgcn_global_load_lds((const __attribute__((address_space(1))) void*)g,
                                   (__attribute__((address_space(3))) void*)l, 16, 0, 0);
}

__device__ __forceinline__ void ld4(const float* p, float& a,float& b,float& c,float& d){
  float4 v = *reinterpret_cast<const float4*>(p); a=v.x; b=v.y; c=v.z; d=v.w;
}
__device__ __forceinline__ float wave_sum(float v){
  #pragma unroll
  for (int off=32; off>0; off>>=1) v += __shfl_down(v, off);
  return v;
}

// bijective XCD swizzle (m204): contiguous lin-ranges per XCD
__device__ __forceinline__ int xcd_swz(int wg, int nwg){
  int q = nwg >> 3, r = nwg & 7;
  int x = wg & 7, i = wg >> 3;
  return (x < r ? x*(q+1) : r*(q+1) + (x-r)*q) + i;
}

// ---------------- fused weight prep: fp32 -> bf16 for 6 weight tensors ----------------
__global__ __launch_bounds__(256) void prep_weights(
    const float* __restrict__ s0, const float* __restrict__ s1,
    const float* __restrict__ s2, const float* __restrict__ s3,
    const float* __restrict__ s4, const float* __restrict__ s5,
    bf16* __restrict__ d0, bf16* __restrict__ d1, bf16* __restrict__ d2,
    bf16* __restrict__ d3, bf16* __restrict__ d4, bf16* __restrict__ d5){
  long i4 = (long)blockIdx.x*256 + threadIdx.x;
  const float* s; bf16* d; long base;
  if      (i4 <  442368){ s=s0; d=d0; base=0; }
  else if (i4 <  589824){ s=s1; d=d1; base=442368; }
  else if (i4 < 1179648){ s=s2; d=d2; base=589824; }
  else if (i4 < 3538944){ s=s3; d=d3; base=1179648; }
  else if (i4 < 4128768){ s=s4; d=d4; base=3538944; }
  else                  { s=s5; d=d5; base=4128768; }
  long j = (i4 - base)*4;
  float4 v = *reinterpret_cast<const float4*>(s + j);
  d[j]   = __float2bfloat16(v.x);
  d[j+1] = __float2bfloat16(v.y);
  d[j+2] = __float2bfloat16(v.z);
  d[j+3] = __float2bfloat16(v.w);
}

// ---------------- fused bias concat (f32 copies) ----------------
__global__ __launch_bounds__(256) void prep_bias(
    const float* __restrict__ cfc_b, const float* __restrict__ eh_b,
    const float* __restrict__ cproj_b, const float* __restrict__ et_b,
    float* __restrict__ bias_h, float* __restrict__ bias_t){
  int i = blockIdx.x*256 + threadIdx.x;
  if (i < 3072)       bias_h[i] = cfc_b[i];
  else if (i < 15360) bias_h[i] = eh_b[i-3072];
  else if (i < 16128) bias_t[i-15360] = cproj_b[i-15360];
  else if (i < 19200) bias_t[i-15360] = et_b[i-16128];
}

// ---------------- row LayerNorm: fp32 in, fp32 out ----------------
__global__ __launch_bounds__(256) void ln_rows(const float* __restrict__ in,
    const float* __restrict__ g, const float* __restrict__ b,
    float* __restrict__ out){
  int row = blockIdx.x;
  const float* x = in + (size_t)row*768;
  float* o = out + (size_t)row*768;
  float s=0.f, s2=0.f;
  for (int d=threadIdx.x; d<768; d+=256){ float v=x[d]; s+=v; s2+=v*v; }
  s = wave_sum(s); s2 = wave_sum(s2);
  __shared__ float red[8];
  __shared__ float stat[2];
  int lane = threadIdx.x & 63, wid = threadIdx.x >> 6;
  if (lane==0){ red[wid]=s; red[4+wid]=s2; }
  __syncthreads();
  if (threadIdx.x==0){
    float S=red[0]+red[1]+red[2]+red[3];
    float S2=red[4]+red[5]+red[6]+red[7];
    float m = S*(1.f/768.f);
    float var = S2*(1.f/768.f) - m*m;
    stat[0]=m; stat[1]=rsqrtf(var + 1e-5f);
  }
  __syncthreads();
  float m=stat[0], inv=stat[1];
  for (int d=threadIdx.x; d<768; d+=256)
    o[d] = (x[d]-m)*inv*g[d] + b[d];
}

// -------- row LayerNorm with split source (rows<M0 from inA, else inB), bf16 out --------
__global__ __launch_bounds__(256) void ln_rows_b_split(const float* __restrict__ inA,
    const float* __restrict__ inB, int M0,
    const float* __restrict__ g, const float* __restrict__ b,
    bf16* __restrict__ out){
  int row = blockIdx.x;
  const float* x = (row < M0) ? inA + (size_t)row*768 : inB + (size_t)(row-M0)*768;
  bf16* o = out + (size_t)row*768;
  float s=0.f, s2=0.f;
  for (int d=threadIdx.x; d<768; d+=256){ float v=x[d]; s+=v; s2+=v*v; }
  s = wave_sum(s); s2 = wave_sum(s2);
  __shared__ float red[8];
  __shared__ float stat[2];
  int lane = threadIdx.x & 63, wid = threadIdx.x >> 6;
  if (lane==0){ red[wid]=s; red[4+wid]=s2; }
  __syncthreads();
  if (threadIdx.x==0){
    float S=red[0]+red[1]+red[2]+red[3];
    float S2=red[4]+red[5]+red[6]+red[7];
    float m = S*(1.f/768.f);
    float var = S2*(1.f/768.f) - m*m;
    stat[0]=m; stat[1]=rsqrtf(var + 1e-5f);
  }
  __syncthreads();
  float m=stat[0], inv=stat[1];
  for (int d=threadIdx.x; d<768; d+=256)
    o[d] = __float2bfloat16((x[d]-m)*inv*g[d] + b[d]);
}

// ---------------- row LayerNorm: fp32 in, bf16 out ----------------
__global__ __launch_bounds__(256) void ln_rows_b(const float* __restrict__ in,
    const float* __restrict__ g, const float* __restrict__ b,
    bf16* __restrict__ out){
  int row = blockIdx.x;
  const float* x = in + (size_t)row*768;
  bf16* o = out + (size_t)row*768;
  float s=0.f, s2=0.f;
  for (int d=threadIdx.x; d<768; d+=256){ float v=x[d]; s+=v; s2+=v*v; }
  s = wave_sum(s); s2 = wave_sum(s2);
  __shared__ float red[8];
  __shared__ float stat[2];
  int lane = threadIdx.x & 63, wid = threadIdx.x >> 6;
  if (lane==0){ red[wid]=s; red[4+wid]=s2; }
  __syncthreads();
  if (threadIdx.x==0){
    float S=red[0]+red[1]+red[2]+red[3];
    float S2=red[4]+red[5]+red[6]+red[7];
    float m = S*(1.f/768.f);
    float var = S2*(1.f/768.f) - m*m;
    stat[0]=m; stat[1]=rsqrtf(var + 1e-5f);
  }
  __syncthreads();
  float m=stat[0], inv=stat[1];
  for (int d=threadIdx.x; d<768; d+=256)
    o[d] = __float2bfloat16((x[d]-m)*inv*g[d] + b[d]);
}

// ---------------- router: one wave per row, x cached in registers ----------------
template<int K>
__global__ __launch_bounds__(256) void router2(const bf16* __restrict__ X,
    const float* __restrict__ W, const float* __restrict__ bias,
    float* __restrict__ out, int rows){
  int row = blockIdx.x*4 + (threadIdx.x>>6);
  int lane = threadIdx.x & 63;
  if (row >= rows) return;
  const bf16* x = X + (size_t)row*K;
  constexpr int NC = K/64;
  float xa[NC];
  #pragma unroll
  for (int c=0;c<NC;++c) xa[c] = b2f(x[c*64 + lane]);
  float lg[5];
  #pragma unroll
  for (int e=0;e<5;++e){
    const float* w = W + (size_t)e*K;
    float p=0.f;
    #pragma unroll
    for (int c=0;c<NC;++c) p += xa[c]*w[c*64 + lane];
    lg[e] = wave_sum(p);
  }
  if (lane==0){
    float mx=-1e30f;
    #pragma unroll
    for (int e=0;e<5;++e){ lg[e] += bias[e]; mx = fmaxf(mx, lg[e]); }
    float s=0.f;
    #pragma unroll
    for (int e=0;e<5;++e){ lg[e]=expf(lg[e]-mx); s+=lg[e]; }
    float inv=1.f/s;
    #pragma unroll
    for (int e=0;e<5;++e) out[(size_t)row*5+e] = lg[e]*inv;
  }
}

// ---------------- msg attention: seq=8 within each b, 12 heads (fp32) ----------------
__global__ __launch_bounds__(64) void msg_attn(const float* __restrict__ mqkv,
    float* __restrict__ mattno){
  int bh = blockIdx.x; int b = bh/12, h = bh%12;
  __shared__ float qs[8][64], ks[8][64], vs[8][64], sc[8][8];
  int lane = threadIdx.x;
  for (int i=lane; i<512; i+=64){
    int t=i>>6, d=i&63;
    size_t base = ((size_t)(b*8+t))*2304 + h*64 + d;
    qs[t][d]=mqkv[base]; ks[t][d]=mqkv[base+768]; vs[t][d]=mqkv[base+1536];
  }
  __syncthreads();
  { int t=lane>>3, m=lane&7; float a=0.f;
    #pragma unroll
    for (int d=0;d<64;++d) a += qs[t][d]*ks[m][d];
    sc[t][m] = a*0.125f; }
  __syncthreads();
  if (lane<8){
    int t=lane; float mx=-1e30f;
    #pragma unroll
    for (int m=0;m<8;++m) mx=fmaxf(mx, sc[t][m]);
    float s=0.f;
    #pragma unroll
    for (int m=0;m<8;++m){ float e=expf(sc[t][m]-mx); sc[t][m]=e; s+=e; }
    float inv=1.f/s;
    #pragma unroll
    for (int m=0;m<8;++m) sc[t][m]*=inv;
  }
  __syncthreads();
  { int t=lane>>3, d0=(lane&7)*8;
    for (int dd=0; dd<8; ++dd){
      int d=d0+dd; float a=0.f;
      #pragma unroll
      for (int m=0;m<8;++m) a += sc[t][m]*vs[m][d];
      mattno[((size_t)(b*8+t))*768 + h*64 + d] = a;
    } }
}

// ================ MFMA attention: seq=198, D=64; block = (bb,h) x 64 q-rows ================
__global__ __launch_bounds__(256) void attn_mfma(const bf16* __restrict__ qkv,
    bf16* __restrict__ attno){
  constexpr int KP = 232;
  __shared__ __align__(16) unsigned short Ks[208*72];
  __shared__ __align__(16) unsigned short Vt[64*KP];
  __shared__ __align__(16) unsigned short Ps[4*16*KP];

  int tid = threadIdx.x;
  int bh = blockIdx.x; int bb = bh/12, h = bh%12;
  int l0 = blockIdx.y*64;
  int wv = tid>>6, ln = tid&63, quad = ln>>4, mrow = ln&15;

  for (int i=tid; i<1584; i+=256){
    int m=i>>3, dc=(i&7)<<3;
    const uint4 kv = *reinterpret_cast<const uint4*>(qkv + ((size_t)(m*32+bb))*2304 + 768 + h*64 + dc);
    *reinterpret_cast<uint4*>(Ks + m*72 + dc) = kv;
    const uint4 vv = *reinterpret_cast<const uint4*>(qkv + ((size_t)(m*32+bb))*2304 + 1536 + h*64 + dc);
    unsigned int w[4] = {vv.x, vv.y, vv.z, vv.w};
    #pragma unroll
    for (int j=0;j<4;++j){
      Vt[(dc+2*j  )*KP + m] = (unsigned short)(w[j] & 0xffff);
      Vt[(dc+2*j+1)*KP + m] = (unsigned short)(w[j] >> 16);
    }
  }
  for (int i=tid; i<10*72; i+=256) Ks[198*72 + i] = 0;
  for (int i=tid; i<64*34; i+=256){ int d=i/34, c=198+(i%34); Vt[d*KP+c] = 0; }
  { unsigned int* pz = reinterpret_cast<unsigned int*>(Ps);
    for (int i=tid; i<4*16*KP/2; i+=256) pz[i] = 0; }

  int ql = l0 + wv*16 + mrow;
  short8 aq[2] = { {0,0,0,0,0,0,0,0}, {0,0,0,0,0,0,0,0} };
  if (ql < 198){
    aq[0] = *reinterpret_cast<const short8*>(qkv + ((size_t)(ql*32+bb))*2304 + h*64 + quad*8);
    aq[1] = *reinterpret_cast<const short8*>(qkv + ((size_t)(ql*32+bb))*2304 + h*64 + 32 + quad*8);
  }
  __syncthreads();

  f32x4 sc[13];
  const f32x4 zero = {0.f,0.f,0.f,0.f};
  #pragma unroll
  for (int t=0;t<13;++t){
    const short8 bk0 = *reinterpret_cast<const short8*>(Ks + (t*16+mrow)*72 + quad*8);
    const short8 bk1 = *reinterpret_cast<const short8*>(Ks + (t*16+mrow)*72 + 32 + quad*8);
    f32x4 a = zero;
    a = __builtin_amdgcn_mfma_f32_16x16x32_bf16(aq[0], bk0, a, 0,0,0);
    a = __builtin_amdgcn_mfma_f32_16x16x32_bf16(aq[1], bk1, a, 0,0,0);
    sc[t] = a * 0.125f;
  }
  if (192 + mrow >= 198) sc[12] = (f32x4){-1e30f,-1e30f,-1e30f,-1e30f};

  float inv[4];
  #pragma unroll
  for (int r=0;r<4;++r){
    float m = -1e30f;
    #pragma unroll
    for (int t=0;t<13;++t) m = fmaxf(m, sc[t][r]);
    #pragma unroll
    for (int msk=1; msk<16; msk<<=1) m = fmaxf(m, __shfl_xor(m, msk));
    float s = 0.f;
    #pragma unroll
    for (int t=0;t<13;++t){ float e = __expf(sc[t][r]-m); sc[t][r]=e; s+=e; }
    #pragma unroll
    for (int msk=1; msk<16; msk<<=1) s += __shfl_xor(s, msk);
    inv[r] = 1.f/s;
  }

  #pragma unroll
  for (int t=0;t<13;++t)
    #pragma unroll
    for (int r=0;r<4;++r)
      Ps[(wv*16 + quad*4+r)*KP + t*16+mrow] = f2bits(sc[t][r]);
  __syncthreads();

  f32x4 o[4] = {zero,zero,zero,zero};
  #pragma unroll
  for (int kc=0;kc<7;++kc){
    const short8 ap = *reinterpret_cast<const short8*>(Ps + (wv*16+mrow)*KP + kc*32 + quad*8);
    #pragma unroll
    for (int nt=0;nt<4;++nt){
      const short8 bv = *reinterpret_cast<const short8*>(Vt + (nt*16+mrow)*KP + kc*32 + quad*8);
      o[nt] = __builtin_amdgcn_mfma_f32_16x16x32_bf16(ap, bv, o[nt], 0,0,0);
    }
  }
  #pragma unroll
  for (int r=0;r<4;++r){
    int l = l0 + wv*16 + quad*4 + r;
    if (l >= 198) continue;
    #pragma unroll
    for (int nt=0;nt<4;++nt){
      int d = nt*16 + mrow;
      attno[((size_t)(l*32+bb))*768 + h*64 + d] = __float2bfloat16(o[nt][r]*inv[r]);
    }
  }
}

// ---------------- small fp32 tiled GEMM for msg branch ----------------
__global__ __launch_bounds__(256) void gemm_nt(const float* __restrict__ A,
    const float* __restrict__ B, const float* __restrict__ bias,
    const float* res, float* C,
    int M, int N, int K){
  __shared__ __align__(16) float As[16][68];
  __shared__ __align__(16) float Bs[16][68];
  int tid=threadIdx.x, tx=tid&15, ty=tid>>4;
  int row0=blockIdx.y*64, col0=blockIdx.x*64;
  int lrow=tid>>2, lk4=(tid&3)*4;
  float acc[4][4]={};
  for (int kb=0; kb<K; kb+=16){
    int gr = row0 + lrow;
    if (gr < M){
      float a0,a1,a2,a3; ld4(A + (size_t)gr*K + kb + lk4, a0,a1,a2,a3);
      As[lk4][lrow]=a0; As[lk4+1][lrow]=a1; As[lk4+2][lrow]=a2; As[lk4+3][lrow]=a3;
    } else {
      As[lk4][lrow]=0.f; As[lk4+1][lrow]=0.f; As[lk4+2][lrow]=0.f; As[lk4+3][lrow]=0.f;
    }
    { float c0,c1,c2,c3; ld4(B + (size_t)(col0+lrow)*K + kb + lk4, c0,c1,c2,c3);
      Bs[lk4][lrow]=c0; Bs[lk4+1][lrow]=c1; Bs[lk4+2][lrow]=c2; Bs[lk4+3][lrow]=c3; }
    __syncthreads();
    #pragma unroll
    for (int kk=0;kk<16;++kk){
      float4 a4 = *reinterpret_cast<const float4*>(&As[kk][ty*4]);
      float4 b4 = *reinterpret_cast<const float4*>(&Bs[kk][tx*4]);
      float av[4]={a4.x,a4.y,a4.z,a4.w};
      float bw[4]={b4.x,b4.y,b4.z,b4.w};
      #pragma unroll
      for (int u=0;u<4;++u)
        #pragma unroll
        for (int v=0;v<4;++v) acc[u][v] += av[u]*bw[v];
    }
    __syncthreads();
  }
  #pragma unroll
  for (int u=0;u<4;++u){
    int gi = row0 + ty*4 + u;
    if (gi >= M) continue;
    #pragma unroll
    for (int v=0;v<4;++v){
      int gj = col0 + tx*4 + v;
      float r = res ? res[(size_t)gi*N+gj] : 0.f;
      float bb = bias ? bias[gj] : 0.f;
      C[(size_t)gi*N+gj] = r + acc[u][v] + bb;
    }
  }
}

// ================= MFMA bf16 GEMM, 128x128 tile, 2x BK=32 per barrier =================
// MODE 0 (QKV): +bias -> bf16 | MODE 1 (WO): +bias+split-residual -> f32
template<int MODE>
__global__ __launch_bounds__(256,3) void gemm_mfma(
    const bf16* __restrict__ A, const bf16* __restrict__ B,
    const float* __restrict__ bias,
    const float* res, const float* res2, int M0,
    float* __restrict__ outf,
    bf16* __restrict__ outb, int M, int N, int K)
{
  __shared__ __align__(16) bf16 As0[4096];
  __shared__ __align__(16) bf16 As1[4096];
  __shared__ __align__(16) bf16 Bs0[4096];
  __shared__ __align__(16) bf16 Bs1[4096];

  int tid=threadIdx.x, wv=tid>>6, ln=tid&63;
  int quad=ln>>4, mrow=ln&15;
  int row0=blockIdx.y*128, col0=blockIdx.x*128;
  int wr=wv>>1, wc=wv&1;

  int c0 = wv*64 + ln;
  int r0 = c0>>2, cc=(c0&3)*8;

  int aoff[4], boff[4];
  #pragma unroll
  for (int i=0;i<4;++i){
    aoff[i] = (wr*64 + i*16 + mrow)*32 + quad*8;
    boff[i] = (wc*64 + i*16 + mrow)*32 + quad*8;
  }

  f32x4 acc[4][4];
  const f32x4 zero = {0.f,0.f,0.f,0.f};
  #pragma unroll
  for (int i=0;i<4;++i)
    #pragma unroll
    for (int j=0;j<4;++j) acc[i][j]=zero;

  const bf16* Ab = A + (size_t)(row0+r0)*K + cc;
  const bf16* Bb = B + (size_t)(col0+r0)*K + cc;
  for (int kb=0; kb<K; kb+=64){
    gload16(Ab + kb,                As0 + wv*512);
    gload16(Ab + (size_t)64*K + kb, As0 + 2048 + wv*512);
    gload16(Bb + kb,                Bs0 + wv*512);
    gload16(Bb + (size_t)64*K + kb, Bs0 + 2048 + wv*512);
    gload16(Ab + kb + 32,                As1 + wv*512);
    gload16(Ab + (size_t)64*K + kb + 32, As1 + 2048 + wv*512);
    gload16(Bb + kb + 32,                Bs1 + wv*512);
    gload16(Bb + (size_t)64*K + kb + 32, Bs1 + 2048 + wv*512);
    __syncthreads();
    short8 af[4], bfr[4];
    #pragma unroll
    for (int i=0;i<4;++i) af[i]  = *reinterpret_cast<const short8*>(As0 + aoff[i]);
    #pragma unroll
    for (int j=0;j<4;++j) bfr[j] = *reinterpret_cast<const short8*>(Bs0 + boff[j]);
    #pragma unroll
    for (int i=0;i<4;++i)
      #pragma unroll
      for (int j=0;j<4;++j)
        acc[i][j] = __builtin_amdgcn_mfma_f32_16x16x32_bf16(af[i], bfr[j], acc[i][j], 0, 0, 0);
    #pragma unroll
    for (int i=0;i<4;++i) af[i]  = *reinterpret_cast<const short8*>(As1 + aoff[i]);
    #pragma unroll
    for (int j=0;j<4;++j) bfr[j] = *reinterpret_cast<const short8*>(Bs1 + boff[j]);
    #pragma unroll
    for (int i=0;i<4;++i)
      #pragma unroll
      for (int j=0;j<4;++j)
        acc[i][j] = __builtin_amdgcn_mfma_f32_16x16x32_bf16(af[i], bfr[j], acc[i][j], 0, 0, 0);
    __syncthreads();
  }

  #pragma unroll
  for (int i=0;i<4;++i){
    #pragma unroll
    for (int r=0;r<4;++r){
      int gi = row0 + wr*64 + i*16 + quad*4 + r;
      if (gi >= M) continue;
      #pragma unroll
      for (int j=0;j<4;++j){
        int gj = col0 + wc*64 + j*16 + mrow;
        if (MODE==0) outb[(size_t)gi*N+gj] = __float2bfloat16(acc[i][j][r] + bias[gj]);
        else {
          float rr = (gi < M0) ? res[(size_t)gi*N+gj] : res2[(size_t)(gi-M0)*N+gj];
          outf[(size_t)gi*N+gj] = acc[i][j][r] + bias[gj] + rr;
        }
      }
    }
  }
}

// ===== MoE fused GEMM v8: 64x64 tile, 3 blocks/CU, XOR-swizzled units ================
// Session-best configuration (rounds 9/13: 934/936 us total). Experts inner (A staged
// once), double-buffered stage-ahead, conflict-free+coalesced unit layout, 3 blocks/CU.
// MODE 0 (heads): out = qgelu(sum_e r_e*(acc_e+bias_e)) -> bf16
// MODE 1 (tails): out = res + sum_e r_e*(acc_e+bias_e) -> f32
template<int MODE>
__global__ __launch_bounds__(256,3) void gemm_moe8(
    const bf16* __restrict__ A, const bf16* __restrict__ B,
    const float* __restrict__ bias, const float* __restrict__ rmat,
    const float* __restrict__ res, float* __restrict__ outf,
    bf16* __restrict__ outb, int M, int N, int K, int NR, int G)
{
  __shared__ __align__(16) bf16 Ls[2][12288];   // 24 units x 512 bf16 = 24KB per buffer

  int tid=threadIdx.x, wv=tid>>6, ln=tid&63;
  int quad=ln>>4, mrow=ln&15;
  int wr=wv>>1, wc=wv&1;           // 2x2 wave grid: 32 rows x 32 cols per wave

  int lin = xcd_swz(blockIdx.x, gridDim.x);
  int gsz = G*NR;
  int grp = lin/gsz, rem = lin - grp*gsz;
  int by = rem / G, bx = grp*G + rem % G;
  int row0 = by*64, col0 = bx*64;

  // fragment read: lane ln needs (row=mrow, chunk=quad) at swizzled pos (bf16 elems)
  int swz = (mrow*4 + (quad ^ ((mrow>>1)&3)))*8;
  int aoff[2], boff[2];
  #pragma unroll
  for (int i=0;i<2;++i) aoff[i] = (wr*2 + i)*512 + swz;            // A units 0..3
  #pragma unroll
  for (int j=0;j<2;++j) boff[j] = (4 + wc*2 + j)*512 + swz;        // B units 4 + e*4 + ..

  const f32x4 zero = {0.f,0.f,0.f,0.f};
  f32x4 acc[5][2][2];
  #pragma unroll
  for (int e=0;e<5;++e)
    #pragma unroll
    for (int i=0;i<2;++i)
      #pragma unroll
      for (int j=0;j<2;++j) acc[e][i][j]=zero;

  // staging lane map (v7): lane ln fetches row (ln>>2), chunk (ln&3)^((ln>>3)&3)
  int srow = ln>>2, schk = (ln&3) ^ ((ln>>3)&3);
  // per-wave unit sources: units u = wv*6..wv*6+5; u<4 -> A unit u; else B(e,rb)
  const bf16* srcp[6];
  #pragma unroll
  for (int k_=0;k_<6;++k_){
    int u = wv*6 + k_;
    if (u < 4){
      srcp[k_] = A + (size_t)(row0 + u*16 + srow)*K + schk*8;
    } else {
      int ue = u-4, e_ = ue>>2, rb_ = ue&3;
      srcp[k_] = B + ((size_t)e_*N + col0 + rb_*16 + srow)*K + schk*8;
    }
  }
  int ubase = wv*6*512;

#define MOE8_STAGE(buf, kb) { \
    _Pragma("unroll") \
    for (int k_=0;k_<6;++k_) \
      gload16(srcp[k_] + (kb), &Ls[buf][ubase + k_*512]); \
  }

  int nk = K >> 5;
  MOE8_STAGE(0, 0);
  __syncthreads();

  int cur = 0;
  for (int t=0; t<nk; ++t){
    if (t+1 < nk){ MOE8_STAGE(cur^1, (t+1)*32); }
    short8 af0 = *reinterpret_cast<const short8*>(&Ls[cur][aoff[0]]);
    short8 af1 = *reinterpret_cast<const short8*>(&Ls[cur][aoff[1]]);
    #pragma unroll
    for (int e=0;e<5;++e){
      const short8 b0 = *reinterpret_cast<const short8*>(&Ls[cur][e*2048 + boff[0]]);
      const short8 b1 = *reinterpret_cast<const short8*>(&Ls[cur][e*2048 + boff[1]]);
      acc[e][0][0] = __builtin_amdgcn_mfma_f32_16x16x32_bf16(af0, b0, acc[e][0][0], 0,0,0);
      acc[e][0][1] = __builtin_amdgcn_mfma_f32_16x16x32_bf16(af0, b1, acc[e][0][1], 0,0,0);
      acc[e][1][0] = __builtin_amdgcn_mfma_f32_16x16x32_bf16(af1, b0, acc[e][1][0], 0,0,0);
      acc[e][1][1] = __builtin_amdgcn_mfma_f32_16x16x32_bf16(af1, b1, acc[e][1][1], 0,0,0);
    }
    __syncthreads();
    cur ^= 1;
  }
#undef MOE8_STAGE

  // epilogue: fold experts with router weights + bias
  float bv[5][2];
  #pragma unroll
  for (int e=0;e<5;++e)
    #pragma unroll
    for (int j=0;j<2;++j)
      bv[e][j] = bias[(size_t)e*N + col0 + wc*32 + j*16 + mrow];

  #pragma unroll
  for (int i=0;i<2;++i){
    #pragma unroll
    for (int r=0;r<4;++r){
      int gi = row0 + wr*32 + i*16 + quad*4 + r;
      if (gi >= M) continue;
      const float* rp = rmat + (size_t)gi*5;
      float w0=rp[0], w1=rp[1], w2=rp[2], w3=rp[3], w4=rp[4];
      #pragma unroll
      for (int j=0;j<2;++j){
        int gj = col0 + wc*32 + j*16 + mrow;
        float v = w0*(acc[0][i][j][r]+bv[0][j])
                + w1*(acc[1][i][j][r]+bv[1][j])
                + w2*(acc[2][i][j][r]+bv[2][j])
                + w3*(acc[3][i][j][r]+bv[3][j])
                + w4*(acc[4][i][j][r]+bv[4][j]);
        if (MODE==0){
          float q = v / (1.f + __expf(-1.702f*v));
          outb[(size_t)gi*N+gj] = __float2bfloat16(q);
        } else {
          outf[(size_t)gi*N+gj] = v + res[(size_t)gi*N+gj];
        }
      }
    }
  }
}

extern "C" void kernel_launch(void* const* d_in, const int* in_sizes, int n_in,
                              void* d_out, int out_size, void* d_ws, size_t ws_size,
                              hipStream_t stream) {
  const float* x         = (const float*)d_in[0];
  const float* msg_fc_w  = (const float*)d_in[1];
  const float* msg_fc_b  = (const float*)d_in[2];
  const float* msg_ln_g  = (const float*)d_in[3];
  const float* msg_ln_b  = (const float*)d_in[4];
  const float* msg_wqkv  = (const float*)d_in[5];
  const float* msg_bqkv  = (const float*)d_in[6];
  const float* msg_wo    = (const float*)d_in[7];
  const float* msg_bo    = (const float*)d_in[8];
  const float* attn_wqkv = (const float*)d_in[9];
  const float* attn_bqkv = (const float*)d_in[10];
  const float* attn_wo   = (const float*)d_in[11];
  const float* attn_bo   = (const float*)d_in[12];
  const float* ln1_g     = (const float*)d_in[13];
  const float* ln1_b     = (const float*)d_in[14];
  const float* ln2_g     = (const float*)d_in[15];
  const float* ln2_b     = (const float*)d_in[16];
  const float* cfc_w     = (const float*)d_in[17];
  const float* cfc_b     = (const float*)d_in[18];
  const float* cproj_w   = (const float*)d_in[19];
  const float* cproj_b   = (const float*)d_in[20];
  const float* eh_w      = (const float*)d_in[21];
  const float* eh_b      = (const float*)d_in[22];
  const float* et_w      = (const float*)d_in[23];
  const float* et_b      = (const float*)d_in[24];
  const float* r1_w      = (const float*)d_in[25];
  const float* r1_b      = (const float*)d_in[26];
  const float* r2_w      = (const float*)d_in[27];
  const float* r2_b      = (const float*)d_in[28];
  float* out = (float*)d_out;

  // ---- workspace layout (float units) ----
  float* ws     = (float*)d_ws;
  float* xc     = ws;                        // 6336*768 f32
  float* bigA   = xc + 4866048;
  bf16*  qkv_b  = (bf16*)bigA;               // qkv: 6400*2304 bf16
  bf16*  oh_b   = (bf16*)bigA;               // oh : 6400*3072 bf16 (reuse)
  float* lnbf   = bigA + 9830400;
  bf16*  lnb_b  = (bf16*)lnbf;
  float* attnof = lnbf + 2457600;
  bf16*  attno_b= (bf16*)attnof;
  float* wqf    = attnof + 2457600;
  bf16*  wq_b   = (bf16*)wqf;
  float* wof    = wqf + 884736;
  bf16*  wo_b   = (bf16*)wof;
  float* whf    = wof + 294912;
  bf16*  wh_b   = (bf16*)whf;
  float* wtf    = whf + 5898240;
  bf16*  wt_b   = (bf16*)wtf;
  float* bias_h = wtf + 5898240;
  float* bias_t = bias_h + 15360;
  float* r1b    = bias_t + 3840;
  float* r2b    = r1b + 32000;
  float* msg    = r2b + 32000;
  float* mln    = msg + 24576;
  float* mqkv   = mln + 24576;
  float* matt   = mqkv + 73728;
  float* msgres = matt + 24576;              // 32*768 f32: msg-branch final output

  // ---- fused weight prep + bias concat ----
  prep_weights<<<dim3(6488064/256), 256, 0, stream>>>(
      attn_wqkv, attn_wo, cfc_w, eh_w, cproj_w, et_w,
      wq_b, wo_b, wh_b, wh_b + 2359296, wt_b, wt_b + 2359296);
  prep_bias<<<dim3(75), 256, 0, stream>>>(cfc_b, eh_b, cproj_b, et_b, bias_h, bias_t);

  // 1. msg branch (fp32, tiny); final output -> msgres (xc memcpy removed)
  gemm_nt<<<dim3(12,1), 256, 0, stream>>>(x, msg_fc_w, msg_fc_b, nullptr, msg, 32, 768, 768);
  ln_rows<<<dim3(32), 256, 0, stream>>>(msg, msg_ln_g, msg_ln_b, mln);
  gemm_nt<<<dim3(36,1), 256, 0, stream>>>(mln, msg_wqkv, msg_bqkv, nullptr, mqkv, 32, 2304, 768);
  msg_attn<<<dim3(48), 64, 0, stream>>>(mqkv, matt);
  gemm_nt<<<dim3(12,1), 256, 0, stream>>>(matt, msg_wo, msg_bo, msg, msgres, 32, 768, 768);
  // 2. ln1 (6336 rows, split source: x rows<6304, msgres after) -> bf16
  ln_rows_b_split<<<dim3(6336), 256, 0, stream>>>(x, msgres, 6304, ln1_g, ln1_b, lnb_b);
  // 3. qkv = ln1 @ Wqkv^T + b (MFMA)
  gemm_mfma<0><<<dim3(18,50), 256, 0, stream>>>(lnb_b, wq_b, attn_bqkv, nullptr, nullptr, 0, nullptr, qkv_b, 6336, 2304, 768);
  // 4. MFMA attention
  attn_mfma<<<dim3(384,4), 256, 0, stream>>>(qkv_b, attno_b);
  // 5. xc = attno @ Wo^T + bo + split-residual (x rows<6304, msgres after)
  gemm_mfma<1><<<dim3(6,50), 256, 0, stream>>>(attno_b, wo_b, attn_bo, x, msgres, 6304, xc, nullptr, 6336, 768, 768);
  // 6. ln2 (6304 rows) -> bf16
  ln_rows_b<<<dim3(6304), 256, 0, stream>>>(xc, ln2_g, ln2_b, lnb_b);
  // 7. r1 router
  router2<768><<<dim3(1576), 256, 0, stream>>>(lnb_b, r1_w, r1_b, r1b, 6304);
  // 8. heads fused MoE v8: 48 cols x 99 rows, 6 cols per XCD group (exact 8 groups)
  gemm_moe8<0><<<dim3(4752), 256, 0, stream>>>(lnb_b, wh_b, bias_h, r1b, nullptr, nullptr, oh_b, 6304, 3072, 768, 99, 6);
  // 9. r2 router (K=3072)
  router2<3072><<<dim3(1576), 256, 0, stream>>>(oh_b, r2_w, r2_b, r2b, 6304);
  // 10. tails fused MoE v8: 12 cols x 99 rows, 1 col per group
  gemm_moe8<1><<<dim3(1188), 256, 0, stream>>>(oh_b, wt_b, bias_t, r2b, xc, out, nullptr, 6304, 768, 3072, 99, 1);
}

// Round 15
// 894.951 us; speedup vs baseline: 1.0487x; 1.0487x over previous
//
#include <hip/hip_runtime.h>
#include <hip/hip_bf16.h>

typedef __hip_bfloat16 bf16;
typedef __attribute__((ext_vector_type(8))) short short8;
typedef __attribute__((ext_vector_type(4))) float f32x4;

__device__ __forceinline__ float b2f(bf16 v){ return __bfloat162float(v); }
__device__ __forceinline__ unsigned short f2bits(float v){
  bf16 h = __float2bfloat16(v);
  return *reinterpret_cast<unsigned short*>(&h);
}

__device__ __forceinline__ void gload16(const bf16* g, bf16* l){
  __builtin_amdgcn_global_load_lds((const __attribute__((address_space(1))) void*)g,
                                   (__attribute__((address_space(3))) void*)l, 16, 0, 0);
}

__device__ __forceinline__ void ld4(const float* p, float& a,float& b,float& c,float& d){
  float4 v = *reinterpret_cast<const float4*>(p); a=v.x; b=v.y; c=v.z; d=v.w;
}
__device__ __forceinline__ float wave_sum(float v){
  #pragma unroll
  for (int off=32; off>0; off>>=1) v += __shfl_down(v, off);
  return v;
}

// bijective XCD swizzle (m204): contiguous lin-ranges per XCD
__device__ __forceinline__ int xcd_swz(int wg, int nwg){
  int q = nwg >> 3, r = nwg & 7;
  int x = wg & 7, i = wg >> 3;
  return (x < r ? x*(q+1) : r*(q+1) + (x-r)*q) + i;
}

// ---------------- fused weight prep: fp32 -> bf16 for 6 weight tensors ----------------
__global__ __launch_bounds__(256) void prep_weights(
    const float* __restrict__ s0, const float* __restrict__ s1,
    const float* __restrict__ s2, const float* __restrict__ s3,
    const float* __restrict__ s4, const float* __restrict__ s5,
    bf16* __restrict__ d0, bf16* __restrict__ d1, bf16* __restrict__ d2,
    bf16* __restrict__ d3, bf16* __restrict__ d4, bf16* __restrict__ d5){
  long i4 = (long)blockIdx.x*256 + threadIdx.x;
  const float* s; bf16* d; long base;
  if      (i4 <  442368){ s=s0; d=d0; base=0; }
  else if (i4 <  589824){ s=s1; d=d1; base=442368; }
  else if (i4 < 1179648){ s=s2; d=d2; base=589824; }
  else if (i4 < 3538944){ s=s3; d=d3; base=1179648; }
  else if (i4 < 4128768){ s=s4; d=d4; base=3538944; }
  else                  { s=s5; d=d5; base=4128768; }
  long j = (i4 - base)*4;
  float4 v = *reinterpret_cast<const float4*>(s + j);
  d[j]   = __float2bfloat16(v.x);
  d[j+1] = __float2bfloat16(v.y);
  d[j+2] = __float2bfloat16(v.z);
  d[j+3] = __float2bfloat16(v.w);
}

// ---------------- fused bias concat (f32 copies) ----------------
__global__ __launch_bounds__(256) void prep_bias(
    const float* __restrict__ cfc_b, const float* __restrict__ eh_b,
    const float* __restrict__ cproj_b, const float* __restrict__ et_b,
    float* __restrict__ bias_h, float* __restrict__ bias_t){
  int i = blockIdx.x*256 + threadIdx.x;
  if (i < 3072)       bias_h[i] = cfc_b[i];
  else if (i < 15360) bias_h[i] = eh_b[i-3072];
  else if (i < 16128) bias_t[i-15360] = cproj_b[i-15360];
  else if (i < 19200) bias_t[i-15360] = et_b[i-16128];
}

// ---------------- row LayerNorm: fp32 in, fp32 out ----------------
__global__ __launch_bounds__(256) void ln_rows(const float* __restrict__ in,
    const float* __restrict__ g, const float* __restrict__ b,
    float* __restrict__ out){
  int row = blockIdx.x;
  const float* x = in + (size_t)row*768;
  float* o = out + (size_t)row*768;
  float s=0.f, s2=0.f;
  for (int d=threadIdx.x; d<768; d+=256){ float v=x[d]; s+=v; s2+=v*v; }
  s = wave_sum(s); s2 = wave_sum(s2);
  __shared__ float red[8];
  __shared__ float stat[2];
  int lane = threadIdx.x & 63, wid = threadIdx.x >> 6;
  if (lane==0){ red[wid]=s; red[4+wid]=s2; }
  __syncthreads();
  if (threadIdx.x==0){
    float S=red[0]+red[1]+red[2]+red[3];
    float S2=red[4]+red[5]+red[6]+red[7];
    float m = S*(1.f/768.f);
    float var = S2*(1.f/768.f) - m*m;
    stat[0]=m; stat[1]=rsqrtf(var + 1e-5f);
  }
  __syncthreads();
  float m=stat[0], inv=stat[1];
  for (int d=threadIdx.x; d<768; d+=256)
    o[d] = (x[d]-m)*inv*g[d] + b[d];
}

// -------- row LayerNorm with split source (rows<M0 from inA, else inB), bf16 out --------
__global__ __launch_bounds__(256) void ln_rows_b_split(const float* __restrict__ inA,
    const float* __restrict__ inB, int M0,
    const float* __restrict__ g, const float* __restrict__ b,
    bf16* __restrict__ out){
  int row = blockIdx.x;
  const float* x = (row < M0) ? inA + (size_t)row*768 : inB + (size_t)(row-M0)*768;
  bf16* o = out + (size_t)row*768;
  float s=0.f, s2=0.f;
  for (int d=threadIdx.x; d<768; d+=256){ float v=x[d]; s+=v; s2+=v*v; }
  s = wave_sum(s); s2 = wave_sum(s2);
  __shared__ float red[8];
  __shared__ float stat[2];
  int lane = threadIdx.x & 63, wid = threadIdx.x >> 6;
  if (lane==0){ red[wid]=s; red[4+wid]=s2; }
  __syncthreads();
  if (threadIdx.x==0){
    float S=red[0]+red[1]+red[2]+red[3];
    float S2=red[4]+red[5]+red[6]+red[7];
    float m = S*(1.f/768.f);
    float var = S2*(1.f/768.f) - m*m;
    stat[0]=m; stat[1]=rsqrtf(var + 1e-5f);
  }
  __syncthreads();
  float m=stat[0], inv=stat[1];
  for (int d=threadIdx.x; d<768; d+=256)
    o[d] = __float2bfloat16((x[d]-m)*inv*g[d] + b[d]);
}

// ---------------- row LayerNorm: fp32 in, bf16 out ----------------
__global__ __launch_bounds__(256) void ln_rows_b(const float* __restrict__ in,
    const float* __restrict__ g, const float* __restrict__ b,
    bf16* __restrict__ out){
  int row = blockIdx.x;
  const float* x = in + (size_t)row*768;
  bf16* o = out + (size_t)row*768;
  float s=0.f, s2=0.f;
  for (int d=threadIdx.x; d<768; d+=256){ float v=x[d]; s+=v; s2+=v*v; }
  s = wave_sum(s); s2 = wave_sum(s2);
  __shared__ float red[8];
  __shared__ float stat[2];
  int lane = threadIdx.x & 63, wid = threadIdx.x >> 6;
  if (lane==0){ red[wid]=s; red[4+wid]=s2; }
  __syncthreads();
  if (threadIdx.x==0){
    float S=red[0]+red[1]+red[2]+red[3];
    float S2=red[4]+red[5]+red[6]+red[7];
    float m = S*(1.f/768.f);
    float var = S2*(1.f/768.f) - m*m;
    stat[0]=m; stat[1]=rsqrtf(var + 1e-5f);
  }
  __syncthreads();
  float m=stat[0], inv=stat[1];
  for (int d=threadIdx.x; d<768; d+=256)
    o[d] = __float2bfloat16((x[d]-m)*inv*g[d] + b[d]);
}

// ---------------- router: one wave per row, x cached in registers ----------------
template<int K>
__global__ __launch_bounds__(256) void router2(const bf16* __restrict__ X,
    const float* __restrict__ W, const float* __restrict__ bias,
    float* __restrict__ out, int rows){
  int row = blockIdx.x*4 + (threadIdx.x>>6);
  int lane = threadIdx.x & 63;
  if (row >= rows) return;
  const bf16* x = X + (size_t)row*K;
  constexpr int NC = K/64;
  float xa[NC];
  #pragma unroll
  for (int c=0;c<NC;++c) xa[c] = b2f(x[c*64 + lane]);
  float lg[5];
  #pragma unroll
  for (int e=0;e<5;++e){
    const float* w = W + (size_t)e*K;
    float p=0.f;
    #pragma unroll
    for (int c=0;c<NC;++c) p += xa[c]*w[c*64 + lane];
    lg[e] = wave_sum(p);
  }
  if (lane==0){
    float mx=-1e30f;
    #pragma unroll
    for (int e=0;e<5;++e){ lg[e] += bias[e]; mx = fmaxf(mx, lg[e]); }
    float s=0.f;
    #pragma unroll
    for (int e=0;e<5;++e){ lg[e]=expf(lg[e]-mx); s+=lg[e]; }
    float inv=1.f/s;
    #pragma unroll
    for (int e=0;e<5;++e) out[(size_t)row*5+e] = lg[e]*inv;
  }
}

// ---------------- msg attention: seq=8 within each b, 12 heads (fp32) ----------------
__global__ __launch_bounds__(64) void msg_attn(const float* __restrict__ mqkv,
    float* __restrict__ mattno){
  int bh = blockIdx.x; int b = bh/12, h = bh%12;
  __shared__ float qs[8][64], ks[8][64], vs[8][64], sc[8][8];
  int lane = threadIdx.x;
  for (int i=lane; i<512; i+=64){
    int t=i>>6, d=i&63;
    size_t base = ((size_t)(b*8+t))*2304 + h*64 + d;
    qs[t][d]=mqkv[base]; ks[t][d]=mqkv[base+768]; vs[t][d]=mqkv[base+1536];
  }
  __syncthreads();
  { int t=lane>>3, m=lane&7; float a=0.f;
    #pragma unroll
    for (int d=0;d<64;++d) a += qs[t][d]*ks[m][d];
    sc[t][m] = a*0.125f; }
  __syncthreads();
  if (lane<8){
    int t=lane; float mx=-1e30f;
    #pragma unroll
    for (int m=0;m<8;++m) mx=fmaxf(mx, sc[t][m]);
    float s=0.f;
    #pragma unroll
    for (int m=0;m<8;++m){ float e=expf(sc[t][m]-mx); sc[t][m]=e; s+=e; }
    float inv=1.f/s;
    #pragma unroll
    for (int m=0;m<8;++m) sc[t][m]*=inv;
  }
  __syncthreads();
  { int t=lane>>3, d0=(lane&7)*8;
    for (int dd=0; dd<8; ++dd){
      int d=d0+dd; float a=0.f;
      #pragma unroll
      for (int m=0;m<8;++m) a += sc[t][m]*vs[m][d];
      mattno[((size_t)(b*8+t))*768 + h*64 + d] = a;
    } }
}

// ================ MFMA attention: seq=198, D=64; block = (bb,h) x 64 q-rows ================
__global__ __launch_bounds__(256) void attn_mfma(const bf16* __restrict__ qkv,
    bf16* __restrict__ attno){
  constexpr int KP = 232;
  __shared__ __align__(16) unsigned short Ks[208*72];
  __shared__ __align__(16) unsigned short Vt[64*KP];
  __shared__ __align__(16) unsigned short Ps[4*16*KP];

  int tid = threadIdx.x;
  int bh = blockIdx.x; int bb = bh/12, h = bh%12;
  int l0 = blockIdx.y*64;
  int wv = tid>>6, ln = tid&63, quad = ln>>4, mrow = ln&15;

  for (int i=tid; i<1584; i+=256){
    int m=i>>3, dc=(i&7)<<3;
    const uint4 kv = *reinterpret_cast<const uint4*>(qkv + ((size_t)(m*32+bb))*2304 + 768 + h*64 + dc);
    *reinterpret_cast<uint4*>(Ks + m*72 + dc) = kv;
    const uint4 vv = *reinterpret_cast<const uint4*>(qkv + ((size_t)(m*32+bb))*2304 + 1536 + h*64 + dc);
    unsigned int w[4] = {vv.x, vv.y, vv.z, vv.w};
    #pragma unroll
    for (int j=0;j<4;++j){
      Vt[(dc+2*j  )*KP + m] = (unsigned short)(w[j] & 0xffff);
      Vt[(dc+2*j+1)*KP + m] = (unsigned short)(w[j] >> 16);
    }
  }
  for (int i=tid; i<10*72; i+=256) Ks[198*72 + i] = 0;
  for (int i=tid; i<64*34; i+=256){ int d=i/34, c=198+(i%34); Vt[d*KP+c] = 0; }
  { unsigned int* pz = reinterpret_cast<unsigned int*>(Ps);
    for (int i=tid; i<4*16*KP/2; i+=256) pz[i] = 0; }

  int ql = l0 + wv*16 + mrow;
  short8 aq[2] = { {0,0,0,0,0,0,0,0}, {0,0,0,0,0,0,0,0} };
  if (ql < 198){
    aq[0] = *reinterpret_cast<const short8*>(qkv + ((size_t)(ql*32+bb))*2304 + h*64 + quad*8);
    aq[1] = *reinterpret_cast<const short8*>(qkv + ((size_t)(ql*32+bb))*2304 + h*64 + 32 + quad*8);
  }
  __syncthreads();

  f32x4 sc[13];
  const f32x4 zero = {0.f,0.f,0.f,0.f};
  #pragma unroll
  for (int t=0;t<13;++t){
    const short8 bk0 = *reinterpret_cast<const short8*>(Ks + (t*16+mrow)*72 + quad*8);
    const short8 bk1 = *reinterpret_cast<const short8*>(Ks + (t*16+mrow)*72 + 32 + quad*8);
    f32x4 a = zero;
    a = __builtin_amdgcn_mfma_f32_16x16x32_bf16(aq[0], bk0, a, 0,0,0);
    a = __builtin_amdgcn_mfma_f32_16x16x32_bf16(aq[1], bk1, a, 0,0,0);
    sc[t] = a * 0.125f;
  }
  if (192 + mrow >= 198) sc[12] = (f32x4){-1e30f,-1e30f,-1e30f,-1e30f};

  float inv[4];
  #pragma unroll
  for (int r=0;r<4;++r){
    float m = -1e30f;
    #pragma unroll
    for (int t=0;t<13;++t) m = fmaxf(m, sc[t][r]);
    #pragma unroll
    for (int msk=1; msk<16; msk<<=1) m = fmaxf(m, __shfl_xor(m, msk));
    float s = 0.f;
    #pragma unroll
    for (int t=0;t<13;++t){ float e = __expf(sc[t][r]-m); sc[t][r]=e; s+=e; }
    #pragma unroll
    for (int msk=1; msk<16; msk<<=1) s += __shfl_xor(s, msk);
    inv[r] = 1.f/s;
  }

  #pragma unroll
  for (int t=0;t<13;++t)
    #pragma unroll
    for (int r=0;r<4;++r)
      Ps[(wv*16 + quad*4+r)*KP + t*16+mrow] = f2bits(sc[t][r]);
  __syncthreads();

  f32x4 o[4] = {zero,zero,zero,zero};
  #pragma unroll
  for (int kc=0;kc<7;++kc){
    const short8 ap = *reinterpret_cast<const short8*>(Ps + (wv*16+mrow)*KP + kc*32 + quad*8);
    #pragma unroll
    for (int nt=0;nt<4;++nt){
      const short8 bv = *reinterpret_cast<const short8*>(Vt + (nt*16+mrow)*KP + kc*32 + quad*8);
      o[nt] = __builtin_amdgcn_mfma_f32_16x16x32_bf16(ap, bv, o[nt], 0,0,0);
    }
  }
  #pragma unroll
  for (int r=0;r<4;++r){
    int l = l0 + wv*16 + quad*4 + r;
    if (l >= 198) continue;
    #pragma unroll
    for (int nt=0;nt<4;++nt){
      int d = nt*16 + mrow;
      attno[((size_t)(l*32+bb))*768 + h*64 + d] = __float2bfloat16(o[nt][r]*inv[r]);
    }
  }
}

// ---------------- small fp32 tiled GEMM for msg branch ----------------
__global__ __launch_bounds__(256) void gemm_nt(const float* __restrict__ A,
    const float* __restrict__ B, const float* __restrict__ bias,
    const float* res, float* C,
    int M, int N, int K){
  __shared__ __align__(16) float As[16][68];
  __shared__ __align__(16) float Bs[16][68];
  int tid=threadIdx.x, tx=tid&15, ty=tid>>4;
  int row0=blockIdx.y*64, col0=blockIdx.x*64;
  int lrow=tid>>2, lk4=(tid&3)*4;
  float acc[4][4]={};
  for (int kb=0; kb<K; kb+=16){
    int gr = row0 + lrow;
    if (gr < M){
      float a0,a1,a2,a3; ld4(A + (size_t)gr*K + kb + lk4, a0,a1,a2,a3);
      As[lk4][lrow]=a0; As[lk4+1][lrow]=a1; As[lk4+2][lrow]=a2; As[lk4+3][lrow]=a3;
    } else {
      As[lk4][lrow]=0.f; As[lk4+1][lrow]=0.f; As[lk4+2][lrow]=0.f; As[lk4+3][lrow]=0.f;
    }
    { float c0,c1,c2,c3; ld4(B + (size_t)(col0+lrow)*K + kb + lk4, c0,c1,c2,c3);
      Bs[lk4][lrow]=c0; Bs[lk4+1][lrow]=c1; Bs[lk4+2][lrow]=c2; Bs[lk4+3][lrow]=c3; }
    __syncthreads();
    #pragma unroll
    for (int kk=0;kk<16;++kk){
      float4 a4 = *reinterpret_cast<const float4*>(&As[kk][ty*4]);
      float4 b4 = *reinterpret_cast<const float4*>(&Bs[kk][tx*4]);
      float av[4]={a4.x,a4.y,a4.z,a4.w};
      float bw[4]={b4.x,b4.y,b4.z,b4.w};
      #pragma unroll
      for (int u=0;u<4;++u)
        #pragma unroll
        for (int v=0;v<4;++v) acc[u][v] += av[u]*bw[v];
    }
    __syncthreads();
  }
  #pragma unroll
  for (int u=0;u<4;++u){
    int gi = row0 + ty*4 + u;
    if (gi >= M) continue;
    #pragma unroll
    for (int v=0;v<4;++v){
      int gj = col0 + tx*4 + v;
      float r = res ? res[(size_t)gi*N+gj] : 0.f;
      float bb = bias ? bias[gj] : 0.f;
      C[(size_t)gi*N+gj] = r + acc[u][v] + bb;
    }
  }
}

// ================= MFMA bf16 GEMM, 128x128 tile, 2x BK=32 per barrier =================
// MODE 0 (QKV): +bias -> bf16 | MODE 1 (WO): +bias+split-residual -> f32
template<int MODE>
__global__ __launch_bounds__(256,3) void gemm_mfma(
    const bf16* __restrict__ A, const bf16* __restrict__ B,
    const float* __restrict__ bias,
    const float* res, const float* res2, int M0,
    float* __restrict__ outf,
    bf16* __restrict__ outb, int M, int N, int K)
{
  __shared__ __align__(16) bf16 As0[4096];
  __shared__ __align__(16) bf16 As1[4096];
  __shared__ __align__(16) bf16 Bs0[4096];
  __shared__ __align__(16) bf16 Bs1[4096];

  int tid=threadIdx.x, wv=tid>>6, ln=tid&63;
  int quad=ln>>4, mrow=ln&15;
  int row0=blockIdx.y*128, col0=blockIdx.x*128;
  int wr=wv>>1, wc=wv&1;

  int c0 = wv*64 + ln;
  int r0 = c0>>2, cc=(c0&3)*8;

  int aoff[4], boff[4];
  #pragma unroll
  for (int i=0;i<4;++i){
    aoff[i] = (wr*64 + i*16 + mrow)*32 + quad*8;
    boff[i] = (wc*64 + i*16 + mrow)*32 + quad*8;
  }

  f32x4 acc[4][4];
  const f32x4 zero = {0.f,0.f,0.f,0.f};
  #pragma unroll
  for (int i=0;i<4;++i)
    #pragma unroll
    for (int j=0;j<4;++j) acc[i][j]=zero;

  const bf16* Ab = A + (size_t)(row0+r0)*K + cc;
  const bf16* Bb = B + (size_t)(col0+r0)*K + cc;
  for (int kb=0; kb<K; kb+=64){
    gload16(Ab + kb,                As0 + wv*512);
    gload16(Ab + (size_t)64*K + kb, As0 + 2048 + wv*512);
    gload16(Bb + kb,                Bs0 + wv*512);
    gload16(Bb + (size_t)64*K + kb, Bs0 + 2048 + wv*512);
    gload16(Ab + kb + 32,                As1 + wv*512);
    gload16(Ab + (size_t)64*K + kb + 32, As1 + 2048 + wv*512);
    gload16(Bb + kb + 32,                Bs1 + wv*512);
    gload16(Bb + (size_t)64*K + kb + 32, Bs1 + 2048 + wv*512);
    __syncthreads();
    short8 af[4], bfr[4];
    #pragma unroll
    for (int i=0;i<4;++i) af[i]  = *reinterpret_cast<const short8*>(As0 + aoff[i]);
    #pragma unroll
    for (int j=0;j<4;++j) bfr[j] = *reinterpret_cast<const short8*>(Bs0 + boff[j]);
    #pragma unroll
    for (int i=0;i<4;++i)
      #pragma unroll
      for (int j=0;j<4;++j)
        acc[i][j] = __builtin_amdgcn_mfma_f32_16x16x32_bf16(af[i], bfr[j], acc[i][j], 0, 0, 0);
    #pragma unroll
    for (int i=0;i<4;++i) af[i]  = *reinterpret_cast<const short8*>(As1 + aoff[i]);
    #pragma unroll
    for (int j=0;j<4;++j) bfr[j] = *reinterpret_cast<const short8*>(Bs1 + boff[j]);
    #pragma unroll
    for (int i=0;i<4;++i)
      #pragma unroll
      for (int j=0;j<4;++j)
        acc[i][j] = __builtin_amdgcn_mfma_f32_16x16x32_bf16(af[i], bfr[j], acc[i][j], 0, 0, 0);
    __syncthreads();
  }

  #pragma unroll
  for (int i=0;i<4;++i){
    #pragma unroll
    for (int r=0;r<4;++r){
      int gi = row0 + wr*64 + i*16 + quad*4 + r;
      if (gi >= M) continue;
      #pragma unroll
      for (int j=0;j<4;++j){
        int gj = col0 + wc*64 + j*16 + mrow;
        if (MODE==0) outb[(size_t)gi*N+gj] = __float2bfloat16(acc[i][j][r] + bias[gj]);
        else {
          float rr = (gi < M0) ? res[(size_t)gi*N+gj] : res2[(size_t)(gi-M0)*N+gj];
          outf[(size_t)gi*N+gj] = acc[i][j][r] + bias[gj] + rr;
        }
      }
    }
  }
}

// ===== MoE fused GEMM v10: 128x64 tile, per-wave 64x32 (DS-read amplification 0.35) ====
// v8 was LDS-read-throughput-bound (144KB reads/CU/K-step = measured cycle budget).
// Larger per-wave tile: reads/K-step per wave = 4 A + 10 B = 14 for 40 MFMA (vs 12/20).
// acc[5][4][2]=160 AGPR + ~70 VGPR -> 2 waves/SIMD; LDS 56KB -> 2 blocks/CU.
// Same XOR-swizzled 1KB units, same __syncthreads schedule, 7 staged units/wave.
// MODE 0 (heads): out = qgelu(sum_e r_e*(acc_e+bias_e)) -> bf16
// MODE 1 (tails): out = res + sum_e r_e*(acc_e+bias_e) -> f32
template<int MODE>
__global__ __launch_bounds__(256,2) void gemm_moe10(
    const bf16* __restrict__ A, const bf16* __restrict__ B,
    const float* __restrict__ bias, const float* __restrict__ rmat,
    const float* __restrict__ res, float* __restrict__ outf,
    bf16* __restrict__ outb, int M, int N, int K, int NR, int G)
{
  __shared__ __align__(16) bf16 Ls[2][14336];   // 28 units x 512 bf16 = 28KB per buffer

  int tid=threadIdx.x, wv=tid>>6, ln=tid&63;
  int quad=ln>>4, mrow=ln&15;
  int wr=wv>>1, wc=wv&1;           // 2x2 wave grid: 64 rows x 32 cols per wave

  int lin = xcd_swz(blockIdx.x, gridDim.x);
  int gsz = G*NR;
  int grp = lin/gsz, rem = lin - grp*gsz;
  int by = rem / G, bx = grp*G + rem % G;
  int row0 = by*128, col0 = bx*64;

  // fragment read: lane ln needs (row=mrow, chunk=quad) at swizzled pos (bf16 elems)
  int swz = (mrow*4 + (quad ^ ((mrow>>1)&3)))*8;
  int aoff[4];
  #pragma unroll
  for (int i=0;i<4;++i) aoff[i] = (wr*4 + i)*512 + swz;            // A units 0..7

  const f32x4 zero = {0.f,0.f,0.f,0.f};
  f32x4 acc[5][4][2];
  #pragma unroll
  for (int e=0;e<5;++e)
    #pragma unroll
    for (int i=0;i<4;++i)
      #pragma unroll
      for (int j=0;j<2;++j) acc[e][i][j]=zero;

  // staging lane map: lane ln fetches row (ln>>2), chunk (ln&3)^((ln>>3)&3)
  int srow = ln>>2, schk = (ln&3) ^ ((ln>>3)&3);
  // per-wave unit sources: units u = wv*7..wv*7+6; u<8 -> A row-unit u; else B(e,cb)
  const bf16* srcp[7];
  #pragma unroll
  for (int k_=0;k_<7;++k_){
    int u = wv*7 + k_;
    if (u < 8){
      srcp[k_] = A + (size_t)(row0 + u*16 + srow)*K + schk*8;
    } else {
      int ue = u-8, e_ = ue>>2, cb_ = ue&3;
      srcp[k_] = B + ((size_t)e_*N + col0 + cb_*16 + srow)*K + schk*8;
    }
  }
  int ubase = wv*7*512;

#define MOE10_STAGE(buf, kb) { \
    _Pragma("unroll") \
    for (int k_=0;k_<7;++k_) \
      gload16(srcp[k_] + (kb), &Ls[buf][ubase + k_*512]); \
  }

  int nk = K >> 5;
  MOE10_STAGE(0, 0);
  __syncthreads();

  int cur = 0;
  for (int t=0; t<nk; ++t){
    if (t+1 < nk){ MOE10_STAGE(cur^1, (t+1)*32); }
    short8 af[4];
    #pragma unroll
    for (int i=0;i<4;++i) af[i] = *reinterpret_cast<const short8*>(&Ls[cur][aoff[i]]);
    #pragma unroll
    for (int e=0;e<5;++e){
      const short8 b0 = *reinterpret_cast<const short8*>(&Ls[cur][(8 + e*4 + wc*2    )*512 + swz]);
      const short8 b1 = *reinterpret_cast<const short8*>(&Ls[cur][(8 + e*4 + wc*2 + 1)*512 + swz]);
      #pragma unroll
      for (int i=0;i<4;++i){
        acc[e][i][0] = __builtin_amdgcn_mfma_f32_16x16x32_bf16(af[i], b0, acc[e][i][0], 0,0,0);
        acc[e][i][1] = __builtin_amdgcn_mfma_f32_16x16x32_bf16(af[i], b1, acc[e][i][1], 0,0,0);
      }
    }
    __syncthreads();
    cur ^= 1;
  }
#undef MOE10_STAGE

  // epilogue: fold experts with router weights + bias
  float bv[5][2];
  #pragma unroll
  for (int e=0;e<5;++e)
    #pragma unroll
    for (int j=0;j<2;++j)
      bv[e][j] = bias[(size_t)e*N + col0 + wc*32 + j*16 + mrow];

  #pragma unroll
  for (int i=0;i<4;++i){
    #pragma unroll
    for (int r=0;r<4;++r){
      int gi = row0 + wr*64 + i*16 + quad*4 + r;
      if (gi >= M) continue;
      const float* rp = rmat + (size_t)gi*5;
      float w0=rp[0], w1=rp[1], w2=rp[2], w3=rp[3], w4=rp[4];
      #pragma unroll
      for (int j=0;j<2;++j){
        int gj = col0 + wc*32 + j*16 + mrow;
        float v = w0*(acc[0][i][j][r]+bv[0][j])
                + w1*(acc[1][i][j][r]+bv[1][j])
                + w2*(acc[2][i][j][r]+bv[2][j])
                + w3*(acc[3][i][j][r]+bv[3][j])
                + w4*(acc[4][i][j][r]+bv[4][j]);
        if (MODE==0){
          float q = v / (1.f + __expf(-1.702f*v));
          outb[(size_t)gi*N+gj] = __float2bfloat16(q);
        } else {
          outf[(size_t)gi*N+gj] = v + res[(size_t)gi*N+gj];
        }
      }
    }
  }
}

extern "C" void kernel_launch(void* const* d_in, const int* in_sizes, int n_in,
                              void* d_out, int out_size, void* d_ws, size_t ws_size,
                              hipStream_t stream) {
  const float* x         = (const float*)d_in[0];
  const float* msg_fc_w  = (const float*)d_in[1];
  const float* msg_fc_b  = (const float*)d_in[2];
  const float* msg_ln_g  = (const float*)d_in[3];
  const float* msg_ln_b  = (const float*)d_in[4];
  const float* msg_wqkv  = (const float*)d_in[5];
  const float* msg_bqkv  = (const float*)d_in[6];
  const float* msg_wo    = (const float*)d_in[7];
  const float* msg_bo    = (const float*)d_in[8];
  const float* attn_wqkv = (const float*)d_in[9];
  const float* attn_bqkv = (const float*)d_in[10];
  const float* attn_wo   = (const float*)d_in[11];
  const float* attn_bo   = (const float*)d_in[12];
  const float* ln1_g     = (const float*)d_in[13];
  const float* ln1_b     = (const float*)d_in[14];
  const float* ln2_g     = (const float*)d_in[15];
  const float* ln2_b     = (const float*)d_in[16];
  const float* cfc_w     = (const float*)d_in[17];
  const float* cfc_b     = (const float*)d_in[18];
  const float* cproj_w   = (const float*)d_in[19];
  const float* cproj_b   = (const float*)d_in[20];
  const float* eh_w      = (const float*)d_in[21];
  const float* eh_b      = (const float*)d_in[22];
  const float* et_w      = (const float*)d_in[23];
  const float* et_b      = (const float*)d_in[24];
  const float* r1_w      = (const float*)d_in[25];
  const float* r1_b      = (const float*)d_in[26];
  const float* r2_w      = (const float*)d_in[27];
  const float* r2_b      = (const float*)d_in[28];
  float* out = (float*)d_out;

  // ---- workspace layout (float units) ----
  float* ws     = (float*)d_ws;
  float* xc     = ws;                        // 6336*768 f32
  float* bigA   = xc + 4866048;
  bf16*  qkv_b  = (bf16*)bigA;               // qkv: 6400*2304 bf16
  bf16*  oh_b   = (bf16*)bigA;               // oh : 6400*3072 bf16 (reuse)
  float* lnbf   = bigA + 9830400;
  bf16*  lnb_b  = (bf16*)lnbf;
  float* attnof = lnbf + 2457600;
  bf16*  attno_b= (bf16*)attnof;
  float* wqf    = attnof + 2457600;
  bf16*  wq_b   = (bf16*)wqf;
  float* wof    = wqf + 884736;
  bf16*  wo_b   = (bf16*)wof;
  float* whf    = wof + 294912;
  bf16*  wh_b   = (bf16*)whf;
  float* wtf    = whf + 5898240;
  bf16*  wt_b   = (bf16*)wtf;
  float* bias_h = wtf + 5898240;
  float* bias_t = bias_h + 15360;
  float* r1b    = bias_t + 3840;
  float* r2b    = r1b + 32000;
  float* msg    = r2b + 32000;
  float* mln    = msg + 24576;
  float* mqkv   = mln + 24576;
  float* matt   = mqkv + 73728;
  float* msgres = matt + 24576;              // 32*768 f32: msg-branch final output

  // ---- fused weight prep + bias concat ----
  prep_weights<<<dim3(6488064/256), 256, 0, stream>>>(
      attn_wqkv, attn_wo, cfc_w, eh_w, cproj_w, et_w,
      wq_b, wo_b, wh_b, wh_b + 2359296, wt_b, wt_b + 2359296);
  prep_bias<<<dim3(75), 256, 0, stream>>>(cfc_b, eh_b, cproj_b, et_b, bias_h, bias_t);

  // 1. msg branch (fp32, tiny); final output -> msgres
  gemm_nt<<<dim3(12,1), 256, 0, stream>>>(x, msg_fc_w, msg_fc_b, nullptr, msg, 32, 768, 768);
  ln_rows<<<dim3(32), 256, 0, stream>>>(msg, msg_ln_g, msg_ln_b, mln);
  gemm_nt<<<dim3(36,1), 256, 0, stream>>>(mln, msg_wqkv, msg_bqkv, nullptr, mqkv, 32, 2304, 768);
  msg_attn<<<dim3(48), 64, 0, stream>>>(mqkv, matt);
  gemm_nt<<<dim3(12,1), 256, 0, stream>>>(matt, msg_wo, msg_bo, msg, msgres, 32, 768, 768);
  // 2. ln1 (6336 rows, split source: x rows<6304, msgres after) -> bf16
  ln_rows_b_split<<<dim3(6336), 256, 0, stream>>>(x, msgres, 6304, ln1_g, ln1_b, lnb_b);
  // 3. qkv = ln1 @ Wqkv^T + b (MFMA)
  gemm_mfma<0><<<dim3(18,50), 256, 0, stream>>>(lnb_b, wq_b, attn_bqkv, nullptr, nullptr, 0, nullptr, qkv_b, 6336, 2304, 768);
  // 4. MFMA attention
  attn_mfma<<<dim3(384,4), 256, 0, stream>>>(qkv_b, attno_b);
  // 5. xc = attno @ Wo^T + bo + split-residual (x rows<6304, msgres after)
  gemm_mfma<1><<<dim3(6,50), 256, 0, stream>>>(attno_b, wo_b, attn_bo, x, msgres, 6304, xc, nullptr, 6336, 768, 768);
  // 6. ln2 (6304 rows) -> bf16
  ln_rows_b<<<dim3(6304), 256, 0, stream>>>(xc, ln2_g, ln2_b, lnb_b);
  // 7. r1 router
  router2<768><<<dim3(1576), 256, 0, stream>>>(lnb_b, r1_w, r1_b, r1b, 6304);
  // 8. heads fused MoE v10: 48 cols x 50 row-blocks (128 rows), 6 cols per XCD group
  gemm_moe10<0><<<dim3(2400), 256, 0, stream>>>(lnb_b, wh_b, bias_h, r1b, nullptr, nullptr, oh_b, 6304, 3072, 768, 50, 6);
  // 9. r2 router (K=3072)
  router2<3072><<<dim3(1576), 256, 0, stream>>>(oh_b, r2_w, r2_b, r2b, 6304);
  // 10. tails fused MoE v10: 12 cols x 50 row-blocks, 1 col per group
  gemm_moe10<1><<<dim3(600), 256, 0, stream>>>(oh_b, wt_b, bias_t, r2b, xc, out, nullptr, 6304, 768, 3072, 50, 1);
}

// Round 16
// 891.034 us; speedup vs baseline: 1.0534x; 1.0044x over previous
//
#include <hip/hip_runtime.h>
#include <hip/hip_bf16.h>

typedef __hip_bfloat16 bf16;
typedef __attribute__((ext_vector_type(8))) short short8;
typedef __attribute__((ext_vector_type(4))) float f32x4;

__device__ __forceinline__ float b2f(bf16 v){ return __bfloat162float(v); }
__device__ __forceinline__ unsigned short f2bits(float v){
  bf16 h = __float2bfloat16(v);
  return *reinterpret_cast<unsigned short*>(&h);
}

__device__ __forceinline__ void gload16(const bf16* g, bf16* l){
  __builtin_amdgcn_global_load_lds((const __attribute__((address_space(1))) void*)g,
                                   (__attribute__((address_space(3))) void*)l, 16, 0, 0);
}

__device__ __forceinline__ void ld4(const float* p, float& a,float& b,float& c,float& d){
  float4 v = *reinterpret_cast<const float4*>(p); a=v.x; b=v.y; c=v.z; d=v.w;
}
__device__ __forceinline__ float wave_sum(float v){
  #pragma unroll
  for (int off=32; off>0; off>>=1) v += __shfl_down(v, off);
  return v;
}

// bijective XCD swizzle (m204): contiguous lin-ranges per XCD
__device__ __forceinline__ int xcd_swz(int wg, int nwg){
  int q = nwg >> 3, r = nwg & 7;
  int x = wg & 7, i = wg >> 3;
  return (x < r ? x*(q+1) : r*(q+1) + (x-r)*q) + i;
}

// ---------------- fused weight prep: fp32 -> bf16 for 6 weight tensors ----------------
__global__ __launch_bounds__(256) void prep_weights(
    const float* __restrict__ s0, const float* __restrict__ s1,
    const float* __restrict__ s2, const float* __restrict__ s3,
    const float* __restrict__ s4, const float* __restrict__ s5,
    bf16* __restrict__ d0, bf16* __restrict__ d1, bf16* __restrict__ d2,
    bf16* __restrict__ d3, bf16* __restrict__ d4, bf16* __restrict__ d5){
  long i4 = (long)blockIdx.x*256 + threadIdx.x;
  const float* s; bf16* d; long base;
  if      (i4 <  442368){ s=s0; d=d0; base=0; }
  else if (i4 <  589824){ s=s1; d=d1; base=442368; }
  else if (i4 < 1179648){ s=s2; d=d2; base=589824; }
  else if (i4 < 3538944){ s=s3; d=d3; base=1179648; }
  else if (i4 < 4128768){ s=s4; d=d4; base=3538944; }
  else                  { s=s5; d=d5; base=4128768; }
  long j = (i4 - base)*4;
  float4 v = *reinterpret_cast<const float4*>(s + j);
  d[j]   = __float2bfloat16(v.x);
  d[j+1] = __float2bfloat16(v.y);
  d[j+2] = __float2bfloat16(v.z);
  d[j+3] = __float2bfloat16(v.w);
}

// ---------------- fused bias concat (f32 copies) ----------------
__global__ __launch_bounds__(256) void prep_bias(
    const float* __restrict__ cfc_b, const float* __restrict__ eh_b,
    const float* __restrict__ cproj_b, const float* __restrict__ et_b,
    float* __restrict__ bias_h, float* __restrict__ bias_t){
  int i = blockIdx.x*256 + threadIdx.x;
  if (i < 3072)       bias_h[i] = cfc_b[i];
  else if (i < 15360) bias_h[i] = eh_b[i-3072];
  else if (i < 16128) bias_t[i-15360] = cproj_b[i-15360];
  else if (i < 19200) bias_t[i-15360] = et_b[i-16128];
}

// ---------------- row LayerNorm: fp32 in, fp32 out ----------------
__global__ __launch_bounds__(256) void ln_rows(const float* __restrict__ in,
    const float* __restrict__ g, const float* __restrict__ b,
    float* __restrict__ out){
  int row = blockIdx.x;
  const float* x = in + (size_t)row*768;
  float* o = out + (size_t)row*768;
  float s=0.f, s2=0.f;
  for (int d=threadIdx.x; d<768; d+=256){ float v=x[d]; s+=v; s2+=v*v; }
  s = wave_sum(s); s2 = wave_sum(s2);
  __shared__ float red[8];
  __shared__ float stat[2];
  int lane = threadIdx.x & 63, wid = threadIdx.x >> 6;
  if (lane==0){ red[wid]=s; red[4+wid]=s2; }
  __syncthreads();
  if (threadIdx.x==0){
    float S=red[0]+red[1]+red[2]+red[3];
    float S2=red[4]+red[5]+red[6]+red[7];
    float m = S*(1.f/768.f);
    float var = S2*(1.f/768.f) - m*m;
    stat[0]=m; stat[1]=rsqrtf(var + 1e-5f);
  }
  __syncthreads();
  float m=stat[0], inv=stat[1];
  for (int d=threadIdx.x; d<768; d+=256)
    o[d] = (x[d]-m)*inv*g[d] + b[d];
}

// -------- row LayerNorm with split source (rows<M0 from inA, else inB), bf16 out --------
__global__ __launch_bounds__(256) void ln_rows_b_split(const float* __restrict__ inA,
    const float* __restrict__ inB, int M0,
    const float* __restrict__ g, const float* __restrict__ b,
    bf16* __restrict__ out){
  int row = blockIdx.x;
  const float* x = (row < M0) ? inA + (size_t)row*768 : inB + (size_t)(row-M0)*768;
  bf16* o = out + (size_t)row*768;
  float s=0.f, s2=0.f;
  for (int d=threadIdx.x; d<768; d+=256){ float v=x[d]; s+=v; s2+=v*v; }
  s = wave_sum(s); s2 = wave_sum(s2);
  __shared__ float red[8];
  __shared__ float stat[2];
  int lane = threadIdx.x & 63, wid = threadIdx.x >> 6;
  if (lane==0){ red[wid]=s; red[4+wid]=s2; }
  __syncthreads();
  if (threadIdx.x==0){
    float S=red[0]+red[1]+red[2]+red[3];
    float S2=red[4]+red[5]+red[6]+red[7];
    float m = S*(1.f/768.f);
    float var = S2*(1.f/768.f) - m*m;
    stat[0]=m; stat[1]=rsqrtf(var + 1e-5f);
  }
  __syncthreads();
  float m=stat[0], inv=stat[1];
  for (int d=threadIdx.x; d<768; d+=256)
    o[d] = __float2bfloat16((x[d]-m)*inv*g[d] + b[d]);
}

// ---------------- row LayerNorm: fp32 in, bf16 out ----------------
__global__ __launch_bounds__(256) void ln_rows_b(const float* __restrict__ in,
    const float* __restrict__ g, const float* __restrict__ b,
    bf16* __restrict__ out){
  int row = blockIdx.x;
  const float* x = in + (size_t)row*768;
  bf16* o = out + (size_t)row*768;
  float s=0.f, s2=0.f;
  for (int d=threadIdx.x; d<768; d+=256){ float v=x[d]; s+=v; s2+=v*v; }
  s = wave_sum(s); s2 = wave_sum(s2);
  __shared__ float red[8];
  __shared__ float stat[2];
  int lane = threadIdx.x & 63, wid = threadIdx.x >> 6;
  if (lane==0){ red[wid]=s; red[4+wid]=s2; }
  __syncthreads();
  if (threadIdx.x==0){
    float S=red[0]+red[1]+red[2]+red[3];
    float S2=red[4]+red[5]+red[6]+red[7];
    float m = S*(1.f/768.f);
    float var = S2*(1.f/768.f) - m*m;
    stat[0]=m; stat[1]=rsqrtf(var + 1e-5f);
  }
  __syncthreads();
  float m=stat[0], inv=stat[1];
  for (int d=threadIdx.x; d<768; d+=256)
    o[d] = __float2bfloat16((x[d]-m)*inv*g[d] + b[d]);
}

// ---------------- router: one wave per row, x cached in registers ----------------
template<int K>
__global__ __launch_bounds__(256) void router2(const bf16* __restrict__ X,
    const float* __restrict__ W, const float* __restrict__ bias,
    float* __restrict__ out, int rows){
  int row = blockIdx.x*4 + (threadIdx.x>>6);
  int lane = threadIdx.x & 63;
  if (row >= rows) return;
  const bf16* x = X + (size_t)row*K;
  constexpr int NC = K/64;
  float xa[NC];
  #pragma unroll
  for (int c=0;c<NC;++c) xa[c] = b2f(x[c*64 + lane]);
  float lg[5];
  #pragma unroll
  for (int e=0;e<5;++e){
    const float* w = W + (size_t)e*K;
    float p=0.f;
    #pragma unroll
    for (int c=0;c<NC;++c) p += xa[c]*w[c*64 + lane];
    lg[e] = wave_sum(p);
  }
  if (lane==0){
    float mx=-1e30f;
    #pragma unroll
    for (int e=0;e<5;++e){ lg[e] += bias[e]; mx = fmaxf(mx, lg[e]); }
    float s=0.f;
    #pragma unroll
    for (int e=0;e<5;++e){ lg[e]=expf(lg[e]-mx); s+=lg[e]; }
    float inv=1.f/s;
    #pragma unroll
    for (int e=0;e<5;++e) out[(size_t)row*5+e] = lg[e]*inv;
  }
}

// ---------------- msg attention: seq=8 within each b, 12 heads (fp32) ----------------
__global__ __launch_bounds__(64) void msg_attn(const float* __restrict__ mqkv,
    float* __restrict__ mattno){
  int bh = blockIdx.x; int b = bh/12, h = bh%12;
  __shared__ float qs[8][64], ks[8][64], vs[8][64], sc[8][8];
  int lane = threadIdx.x;
  for (int i=lane; i<512; i+=64){
    int t=i>>6, d=i&63;
    size_t base = ((size_t)(b*8+t))*2304 + h*64 + d;
    qs[t][d]=mqkv[base]; ks[t][d]=mqkv[base+768]; vs[t][d]=mqkv[base+1536];
  }
  __syncthreads();
  { int t=lane>>3, m=lane&7; float a=0.f;
    #pragma unroll
    for (int d=0;d<64;++d) a += qs[t][d]*ks[m][d];
    sc[t][m] = a*0.125f; }
  __syncthreads();
  if (lane<8){
    int t=lane; float mx=-1e30f;
    #pragma unroll
    for (int m=0;m<8;++m) mx=fmaxf(mx, sc[t][m]);
    float s=0.f;
    #pragma unroll
    for (int m=0;m<8;++m){ float e=expf(sc[t][m]-mx); sc[t][m]=e; s+=e; }
    float inv=1.f/s;
    #pragma unroll
    for (int m=0;m<8;++m) sc[t][m]*=inv;
  }
  __syncthreads();
  { int t=lane>>3, d0=(lane&7)*8;
    for (int dd=0; dd<8; ++dd){
      int d=d0+dd; float a=0.f;
      #pragma unroll
      for (int m=0;m<8;++m) a += sc[t][m]*vs[m][d];
      mattno[((size_t)(b*8+t))*768 + h*64 + d] = a;
    } }
}

// ================ MFMA attention: seq=198, D=64; block = (bb,h) x 64 q-rows ================
__global__ __launch_bounds__(256) void attn_mfma(const bf16* __restrict__ qkv,
    bf16* __restrict__ attno){
  constexpr int KP = 232;
  __shared__ __align__(16) unsigned short Ks[208*72];
  __shared__ __align__(16) unsigned short Vt[64*KP];
  __shared__ __align__(16) unsigned short Ps[4*16*KP];

  int tid = threadIdx.x;
  int bh = blockIdx.x; int bb = bh/12, h = bh%12;
  int l0 = blockIdx.y*64;
  int wv = tid>>6, ln = tid&63, quad = ln>>4, mrow = ln&15;

  for (int i=tid; i<1584; i+=256){
    int m=i>>3, dc=(i&7)<<3;
    const uint4 kv = *reinterpret_cast<const uint4*>(qkv + ((size_t)(m*32+bb))*2304 + 768 + h*64 + dc);
    *reinterpret_cast<uint4*>(Ks + m*72 + dc) = kv;
    const uint4 vv = *reinterpret_cast<const uint4*>(qkv + ((size_t)(m*32+bb))*2304 + 1536 + h*64 + dc);
    unsigned int w[4] = {vv.x, vv.y, vv.z, vv.w};
    #pragma unroll
    for (int j=0;j<4;++j){
      Vt[(dc+2*j  )*KP + m] = (unsigned short)(w[j] & 0xffff);
      Vt[(dc+2*j+1)*KP + m] = (unsigned short)(w[j] >> 16);
    }
  }
  for (int i=tid; i<10*72; i+=256) Ks[198*72 + i] = 0;
  for (int i=tid; i<64*34; i+=256){ int d=i/34, c=198+(i%34); Vt[d*KP+c] = 0; }
  { unsigned int* pz = reinterpret_cast<unsigned int*>(Ps);
    for (int i=tid; i<4*16*KP/2; i+=256) pz[i] = 0; }

  int ql = l0 + wv*16 + mrow;
  short8 aq[2] = { {0,0,0,0,0,0,0,0}, {0,0,0,0,0,0,0,0} };
  if (ql < 198){
    aq[0] = *reinterpret_cast<const short8*>(qkv + ((size_t)(ql*32+bb))*2304 + h*64 + quad*8);
    aq[1] = *reinterpret_cast<const short8*>(qkv + ((size_t)(ql*32+bb))*2304 + h*64 + 32 + quad*8);
  }
  __syncthreads();

  f32x4 sc[13];
  const f32x4 zero = {0.f,0.f,0.f,0.f};
  #pragma unroll
  for (int t=0;t<13;++t){
    const short8 bk0 = *reinterpret_cast<const short8*>(Ks + (t*16+mrow)*72 + quad*8);
    const short8 bk1 = *reinterpret_cast<const short8*>(Ks + (t*16+mrow)*72 + 32 + quad*8);
    f32x4 a = zero;
    a = __builtin_amdgcn_mfma_f32_16x16x32_bf16(aq[0], bk0, a, 0,0,0);
    a = __builtin_amdgcn_mfma_f32_16x16x32_bf16(aq[1], bk1, a, 0,0,0);
    sc[t] = a * 0.125f;
  }
  if (192 + mrow >= 198) sc[12] = (f32x4){-1e30f,-1e30f,-1e30f,-1e30f};

  float inv[4];
  #pragma unroll
  for (int r=0;r<4;++r){
    float m = -1e30f;
    #pragma unroll
    for (int t=0;t<13;++t) m = fmaxf(m, sc[t][r]);
    #pragma unroll
    for (int msk=1; msk<16; msk<<=1) m = fmaxf(m, __shfl_xor(m, msk));
    float s = 0.f;
    #pragma unroll
    for (int t=0;t<13;++t){ float e = __expf(sc[t][r]-m); sc[t][r]=e; s+=e; }
    #pragma unroll
    for (int msk=1; msk<16; msk<<=1) s += __shfl_xor(s, msk);
    inv[r] = 1.f/s;
  }

  #pragma unroll
  for (int t=0;t<13;++t)
    #pragma unroll
    for (int r=0;r<4;++r)
      Ps[(wv*16 + quad*4+r)*KP + t*16+mrow] = f2bits(sc[t][r]);
  __syncthreads();

  f32x4 o[4] = {zero,zero,zero,zero};
  #pragma unroll
  for (int kc=0;kc<7;++kc){
    const short8 ap = *reinterpret_cast<const short8*>(Ps + (wv*16+mrow)*KP + kc*32 + quad*8);
    #pragma unroll
    for (int nt=0;nt<4;++nt){
      const short8 bv = *reinterpret_cast<const short8*>(Vt + (nt*16+mrow)*KP + kc*32 + quad*8);
      o[nt] = __builtin_amdgcn_mfma_f32_16x16x32_bf16(ap, bv, o[nt], 0,0,0);
    }
  }
  #pragma unroll
  for (int r=0;r<4;++r){
    int l = l0 + wv*16 + quad*4 + r;
    if (l >= 198) continue;
    #pragma unroll
    for (int nt=0;nt<4;++nt){
      int d = nt*16 + mrow;
      attno[((size_t)(l*32+bb))*768 + h*64 + d] = __float2bfloat16(o[nt][r]*inv[r]);
    }
  }
}

// ---------------- small fp32 tiled GEMM for msg branch ----------------
__global__ __launch_bounds__(256) void gemm_nt(const float* __restrict__ A,
    const float* __restrict__ B, const float* __restrict__ bias,
    const float* res, float* C,
    int M, int N, int K){
  __shared__ __align__(16) float As[16][68];
  __shared__ __align__(16) float Bs[16][68];
  int tid=threadIdx.x, tx=tid&15, ty=tid>>4;
  int row0=blockIdx.y*64, col0=blockIdx.x*64;
  int lrow=tid>>2, lk4=(tid&3)*4;
  float acc[4][4]={};
  for (int kb=0; kb<K; kb+=16){
    int gr = row0 + lrow;
    if (gr < M){
      float a0,a1,a2,a3; ld4(A + (size_t)gr*K + kb + lk4, a0,a1,a2,a3);
      As[lk4][lrow]=a0; As[lk4+1][lrow]=a1; As[lk4+2][lrow]=a2; As[lk4+3][lrow]=a3;
    } else {
      As[lk4][lrow]=0.f; As[lk4+1][lrow]=0.f; As[lk4+2][lrow]=0.f; As[lk4+3][lrow]=0.f;
    }
    { float c0,c1,c2,c3; ld4(B + (size_t)(col0+lrow)*K + kb + lk4, c0,c1,c2,c3);
      Bs[lk4][lrow]=c0; Bs[lk4+1][lrow]=c1; Bs[lk4+2][lrow]=c2; Bs[lk4+3][lrow]=c3; }
    __syncthreads();
    #pragma unroll
    for (int kk=0;kk<16;++kk){
      float4 a4 = *reinterpret_cast<const float4*>(&As[kk][ty*4]);
      float4 b4 = *reinterpret_cast<const float4*>(&Bs[kk][tx*4]);
      float av[4]={a4.x,a4.y,a4.z,a4.w};
      float bw[4]={b4.x,b4.y,b4.z,b4.w};
      #pragma unroll
      for (int u=0;u<4;++u)
        #pragma unroll
        for (int v=0;v<4;++v) acc[u][v] += av[u]*bw[v];
    }
    __syncthreads();
  }
  #pragma unroll
  for (int u=0;u<4;++u){
    int gi = row0 + ty*4 + u;
    if (gi >= M) continue;
    #pragma unroll
    for (int v=0;v<4;++v){
      int gj = col0 + tx*4 + v;
      float r = res ? res[(size_t)gi*N+gj] : 0.f;
      float bb = bias ? bias[gj] : 0.f;
      C[(size_t)gi*N+gj] = r + acc[u][v] + bb;
    }
  }
}

// ================= MFMA bf16 GEMM, 128x128 tile, 2x BK=32 per barrier =================
// MODE 0 (QKV): +bias -> bf16 | MODE 1 (WO): +bias+split-residual -> f32
template<int MODE>
__global__ __launch_bounds__(256,3) void gemm_mfma(
    const bf16* __restrict__ A, const bf16* __restrict__ B,
    const float* __restrict__ bias,
    const float* res, const float* res2, int M0,
    float* __restrict__ outf,
    bf16* __restrict__ outb, int M, int N, int K)
{
  __shared__ __align__(16) bf16 As0[4096];
  __shared__ __align__(16) bf16 As1[4096];
  __shared__ __align__(16) bf16 Bs0[4096];
  __shared__ __align__(16) bf16 Bs1[4096];

  int tid=threadIdx.x, wv=tid>>6, ln=tid&63;
  int quad=ln>>4, mrow=ln&15;
  int row0=blockIdx.y*128, col0=blockIdx.x*128;
  int wr=wv>>1, wc=wv&1;

  int c0 = wv*64 + ln;
  int r0 = c0>>2, cc=(c0&3)*8;

  int aoff[4], boff[4];
  #pragma unroll
  for (int i=0;i<4;++i){
    aoff[i] = (wr*64 + i*16 + mrow)*32 + quad*8;
    boff[i] = (wc*64 + i*16 + mrow)*32 + quad*8;
  }

  f32x4 acc[4][4];
  const f32x4 zero = {0.f,0.f,0.f,0.f};
  #pragma unroll
  for (int i=0;i<4;++i)
    #pragma unroll
    for (int j=0;j<4;++j) acc[i][j]=zero;

  const bf16* Ab = A + (size_t)(row0+r0)*K + cc;
  const bf16* Bb = B + (size_t)(col0+r0)*K + cc;
  for (int kb=0; kb<K; kb+=64){
    gload16(Ab + kb,                As0 + wv*512);
    gload16(Ab + (size_t)64*K + kb, As0 + 2048 + wv*512);
    gload16(Bb + kb,                Bs0 + wv*512);
    gload16(Bb + (size_t)64*K + kb, Bs0 + 2048 + wv*512);
    gload16(Ab + kb + 32,                As1 + wv*512);
    gload16(Ab + (size_t)64*K + kb + 32, As1 + 2048 + wv*512);
    gload16(Bb + kb + 32,                Bs1 + wv*512);
    gload16(Bb + (size_t)64*K + kb + 32, Bs1 + 2048 + wv*512);
    __syncthreads();
    short8 af[4], bfr[4];
    #pragma unroll
    for (int i=0;i<4;++i) af[i]  = *reinterpret_cast<const short8*>(As0 + aoff[i]);
    #pragma unroll
    for (int j=0;j<4;++j) bfr[j] = *reinterpret_cast<const short8*>(Bs0 + boff[j]);
    #pragma unroll
    for (int i=0;i<4;++i)
      #pragma unroll
      for (int j=0;j<4;++j)
        acc[i][j] = __builtin_amdgcn_mfma_f32_16x16x32_bf16(af[i], bfr[j], acc[i][j], 0, 0, 0);
    #pragma unroll
    for (int i=0;i<4;++i) af[i]  = *reinterpret_cast<const short8*>(As1 + aoff[i]);
    #pragma unroll
    for (int j=0;j<4;++j) bfr[j] = *reinterpret_cast<const short8*>(Bs1 + boff[j]);
    #pragma unroll
    for (int i=0;i<4;++i)
      #pragma unroll
      for (int j=0;j<4;++j)
        acc[i][j] = __builtin_amdgcn_mfma_f32_16x16x32_bf16(af[i], bfr[j], acc[i][j], 0, 0, 0);
    __syncthreads();
  }

  #pragma unroll
  for (int i=0;i<4;++i){
    #pragma unroll
    for (int r=0;r<4;++r){
      int gi = row0 + wr*64 + i*16 + quad*4 + r;
      if (gi >= M) continue;
      #pragma unroll
      for (int j=0;j<4;++j){
        int gj = col0 + wc*64 + j*16 + mrow;
        if (MODE==0) outb[(size_t)gi*N+gj] = __float2bfloat16(acc[i][j][r] + bias[gj]);
        else {
          float rr = (gi < M0) ? res[(size_t)gi*N+gj] : res2[(size_t)(gi-M0)*N+gj];
          outf[(size_t)gi*N+gj] = acc[i][j][r] + bias[gj] + rr;
        }
      }
    }
  }
}

// ===== MoE fused GEMM v11: v10 (128x64 tile, amp 0.35) + pointer diet for 2 blocks/CU ===
// v10 ran at 1 block/CU: VGPR 108 + 160 acc = 268 > 256. Replace srcp[7] (14 VGPR) with
// one base pointer + 7 x 32-bit element offsets (all sources live in the same d_ws
// allocation; diffs < 2^31). Target VGPR <= 96 so 2 waves/SIMD -> 2 blocks/CU.
// MODE 0 (heads): out = qgelu(sum_e r_e*(acc_e+bias_e)) -> bf16
// MODE 1 (tails): out = res + sum_e r_e*(acc_e+bias_e) -> f32
template<int MODE>
__global__ __launch_bounds__(256,2) void gemm_moe11(
    const bf16* __restrict__ A, const bf16* __restrict__ B,
    const float* __restrict__ bias, const float* __restrict__ rmat,
    const float* __restrict__ res, float* __restrict__ outf,
    bf16* __restrict__ outb, int M, int N, int K, int NR, int G)
{
  __shared__ __align__(16) bf16 Ls[2][14336];   // 28 units x 512 bf16 = 28KB per buffer

  int tid=threadIdx.x, wv=tid>>6, ln=tid&63;
  int quad=ln>>4, mrow=ln&15;
  int wr=wv>>1, wc=wv&1;           // 2x2 wave grid: 64 rows x 32 cols per wave

  int lin = xcd_swz(blockIdx.x, gridDim.x);
  int gsz = G*NR;
  int grp = lin/gsz, rem = lin - grp*gsz;
  int by = rem / G, bx = grp*G + rem % G;
  int row0 = by*128, col0 = bx*64;

  // fragment read: lane ln needs (row=mrow, chunk=quad) at swizzled pos (bf16 elems)
  int swz = (mrow*4 + (quad ^ ((mrow>>1)&3)))*8;
  int aoff[4];
  #pragma unroll
  for (int i=0;i<4;++i) aoff[i] = (wr*4 + i)*512 + swz;            // A units 0..7

  const f32x4 zero = {0.f,0.f,0.f,0.f};
  f32x4 acc[5][4][2];
  #pragma unroll
  for (int e=0;e<5;++e)
    #pragma unroll
    for (int i=0;i<4;++i)
      #pragma unroll
      for (int j=0;j<2;++j) acc[e][i][j]=zero;

  // staging lane map: lane ln fetches row (ln>>2), chunk (ln&3)^((ln>>3)&3)
  int srow = ln>>2, schk = (ln&3) ^ ((ln>>3)&3);
  // per-wave unit sources as base + 32-bit element offsets (register diet):
  // units u = wv*7..wv*7+6; u<8 -> A row-unit u; else B(e,cb). A and B both live in d_ws.
  const bf16* base0;
  int offs[7];
  {
    const bf16* p[7];
    #pragma unroll
    for (int k_=0;k_<7;++k_){
      int u = wv*7 + k_;
      if (u < 8){
        p[k_] = A + (size_t)(row0 + u*16 + srow)*K + schk*8;
      } else {
        int ue = u-8, e_ = ue>>2, cb_ = ue&3;
        p[k_] = B + ((size_t)e_*N + col0 + cb_*16 + srow)*K + schk*8;
      }
    }
    base0 = p[0];
    #pragma unroll
    for (int k_=0;k_<7;++k_) offs[k_] = (int)(p[k_] - base0);
  }
  int ubase = wv*7*512;

#define MOE11_STAGE(buf, kb) { \
    _Pragma("unroll") \
    for (int k_=0;k_<7;++k_) \
      gload16(base0 + offs[k_] + (kb), &Ls[buf][ubase + k_*512]); \
  }

  int nk = K >> 5;
  MOE11_STAGE(0, 0);
  __syncthreads();

  int cur = 0;
  for (int t=0; t<nk; ++t){
    if (t+1 < nk){ MOE11_STAGE(cur^1, (t+1)*32); }
    short8 af[4];
    #pragma unroll
    for (int i=0;i<4;++i) af[i] = *reinterpret_cast<const short8*>(&Ls[cur][aoff[i]]);
    #pragma unroll
    for (int e=0;e<5;++e){
      const short8 b0 = *reinterpret_cast<const short8*>(&Ls[cur][(8 + e*4 + wc*2    )*512 + swz]);
      const short8 b1 = *reinterpret_cast<const short8*>(&Ls[cur][(8 + e*4 + wc*2 + 1)*512 + swz]);
      #pragma unroll
      for (int i=0;i<4;++i){
        acc[e][i][0] = __builtin_amdgcn_mfma_f32_16x16x32_bf16(af[i], b0, acc[e][i][0], 0,0,0);
        acc[e][i][1] = __builtin_amdgcn_mfma_f32_16x16x32_bf16(af[i], b1, acc[e][i][1], 0,0,0);
      }
    }
    __syncthreads();
    cur ^= 1;
  }
#undef MOE11_STAGE

  // epilogue: fold experts with router weights + bias
  float bv[5][2];
  #pragma unroll
  for (int e=0;e<5;++e)
    #pragma unroll
    for (int j=0;j<2;++j)
      bv[e][j] = bias[(size_t)e*N + col0 + wc*32 + j*16 + mrow];

  #pragma unroll
  for (int i=0;i<4;++i){
    #pragma unroll
    for (int r=0;r<4;++r){
      int gi = row0 + wr*64 + i*16 + quad*4 + r;
      if (gi >= M) continue;
      const float* rp = rmat + (size_t)gi*5;
      float w0=rp[0], w1=rp[1], w2=rp[2], w3=rp[3], w4=rp[4];
      #pragma unroll
      for (int j=0;j<2;++j){
        int gj = col0 + wc*32 + j*16 + mrow;
        float v = w0*(acc[0][i][j][r]+bv[0][j])
                + w1*(acc[1][i][j][r]+bv[1][j])
                + w2*(acc[2][i][j][r]+bv[2][j])
                + w3*(acc[3][i][j][r]+bv[3][j])
                + w4*(acc[4][i][j][r]+bv[4][j]);
        if (MODE==0){
          float q = v / (1.f + __expf(-1.702f*v));
          outb[(size_t)gi*N+gj] = __float2bfloat16(q);
        } else {
          outf[(size_t)gi*N+gj] = v + res[(size_t)gi*N+gj];
        }
      }
    }
  }
}

extern "C" void kernel_launch(void* const* d_in, const int* in_sizes, int n_in,
                              void* d_out, int out_size, void* d_ws, size_t ws_size,
                              hipStream_t stream) {
  const float* x         = (const float*)d_in[0];
  const float* msg_fc_w  = (const float*)d_in[1];
  const float* msg_fc_b  = (const float*)d_in[2];
  const float* msg_ln_g  = (const float*)d_in[3];
  const float* msg_ln_b  = (const float*)d_in[4];
  const float* msg_wqkv  = (const float*)d_in[5];
  const float* msg_bqkv  = (const float*)d_in[6];
  const float* msg_wo    = (const float*)d_in[7];
  const float* msg_bo    = (const float*)d_in[8];
  const float* attn_wqkv = (const float*)d_in[9];
  const float* attn_bqkv = (const float*)d_in[10];
  const float* attn_wo   = (const float*)d_in[11];
  const float* attn_bo   = (const float*)d_in[12];
  const float* ln1_g     = (const float*)d_in[13];
  const float* ln1_b     = (const float*)d_in[14];
  const float* ln2_g     = (const float*)d_in[15];
  const float* ln2_b     = (const float*)d_in[16];
  const float* cfc_w     = (const float*)d_in[17];
  const float* cfc_b     = (const float*)d_in[18];
  const float* cproj_w   = (const float*)d_in[19];
  const float* cproj_b   = (const float*)d_in[20];
  const float* eh_w      = (const float*)d_in[21];
  const float* eh_b      = (const float*)d_in[22];
  const float* et_w      = (const float*)d_in[23];
  const float* et_b      = (const float*)d_in[24];
  const float* r1_w      = (const float*)d_in[25];
  const float* r1_b      = (const float*)d_in[26];
  const float* r2_w      = (const float*)d_in[27];
  const float* r2_b      = (const float*)d_in[28];
  float* out = (float*)d_out;

  // ---- workspace layout (float units) ----
  float* ws     = (float*)d_ws;
  float* xc     = ws;                        // 6336*768 f32
  float* bigA   = xc + 4866048;
  bf16*  qkv_b  = (bf16*)bigA;               // qkv: 6400*2304 bf16
  bf16*  oh_b   = (bf16*)bigA;               // oh : 6400*3072 bf16 (reuse)
  float* lnbf   = bigA + 9830400;
  bf16*  lnb_b  = (bf16*)lnbf;
  float* attnof = lnbf + 2457600;
  bf16*  attno_b= (bf16*)attnof;
  float* wqf    = attnof + 2457600;
  bf16*  wq_b   = (bf16*)wqf;
  float* wof    = wqf + 884736;
  bf16*  wo_b   = (bf16*)wof;
  float* whf    = wof + 294912;
  bf16*  wh_b   = (bf16*)whf;
  float* wtf    = whf + 5898240;
  bf16*  wt_b   = (bf16*)wtf;
  float* bias_h = wtf + 5898240;
  float* bias_t = bias_h + 15360;
  float* r1b    = bias_t + 3840;
  float* r2b    = r1b + 32000;
  float* msg    = r2b + 32000;
  float* mln    = msg + 24576;
  float* mqkv   = mln + 24576;
  float* matt   = mqkv + 73728;
  float* msgres = matt + 24576;              // 32*768 f32: msg-branch final output

  // ---- fused weight prep + bias concat ----
  prep_weights<<<dim3(6488064/256), 256, 0, stream>>>(
      attn_wqkv, attn_wo, cfc_w, eh_w, cproj_w, et_w,
      wq_b, wo_b, wh_b, wh_b + 2359296, wt_b, wt_b + 2359296);
  prep_bias<<<dim3(75), 256, 0, stream>>>(cfc_b, eh_b, cproj_b, et_b, bias_h, bias_t);

  // 1. msg branch (fp32, tiny); final output -> msgres
  gemm_nt<<<dim3(12,1), 256, 0, stream>>>(x, msg_fc_w, msg_fc_b, nullptr, msg, 32, 768, 768);
  ln_rows<<<dim3(32), 256, 0, stream>>>(msg, msg_ln_g, msg_ln_b, mln);
  gemm_nt<<<dim3(36,1), 256, 0, stream>>>(mln, msg_wqkv, msg_bqkv, nullptr, mqkv, 32, 2304, 768);
  msg_attn<<<dim3(48), 64, 0, stream>>>(mqkv, matt);
  gemm_nt<<<dim3(12,1), 256, 0, stream>>>(matt, msg_wo, msg_bo, msg, msgres, 32, 768, 768);
  // 2. ln1 (6336 rows, split source: x rows<6304, msgres after) -> bf16
  ln_rows_b_split<<<dim3(6336), 256, 0, stream>>>(x, msgres, 6304, ln1_g, ln1_b, lnb_b);
  // 3. qkv = ln1 @ Wqkv^T + b (MFMA)
  gemm_mfma<0><<<dim3(18,50), 256, 0, stream>>>(lnb_b, wq_b, attn_bqkv, nullptr, nullptr, 0, nullptr, qkv_b, 6336, 2304, 768);
  // 4. MFMA attention
  attn_mfma<<<dim3(384,4), 256, 0, stream>>>(qkv_b, attno_b);
  // 5. xc = attno @ Wo^T + bo + split-residual (x rows<6304, msgres after)
  gemm_mfma<1><<<dim3(6,50), 256, 0, stream>>>(attno_b, wo_b, attn_bo, x, msgres, 6304, xc, nullptr, 6336, 768, 768);
  // 6. ln2 (6304 rows) -> bf16
  ln_rows_b<<<dim3(6304), 256, 0, stream>>>(xc, ln2_g, ln2_b, lnb_b);
  // 7. r1 router
  router2<768><<<dim3(1576), 256, 0, stream>>>(lnb_b, r1_w, r1_b, r1b, 6304);
  // 8. heads fused MoE v11: 48 cols x 50 row-blocks (128 rows), 6 cols per XCD group
  gemm_moe11<0><<<dim3(2400), 256, 0, stream>>>(lnb_b, wh_b, bias_h, r1b, nullptr, nullptr, oh_b, 6304, 3072, 768, 50, 6);
  // 9. r2 router (K=3072)
  router2<3072><<<dim3(1576), 256, 0, stream>>>(oh_b, r2_w, r2_b, r2b, 6304);
  // 10. tails fused MoE v11: 12 cols x 50 row-blocks, 1 col per group
  gemm_moe11<1><<<dim3(600), 256, 0, stream>>>(oh_b, wt_b, bias_t, r2b, xc, out, nullptr, 6304, 768, 3072, 50, 1);
}